// Round 11
// baseline (1076.014 us; speedup 1.0000x reference)
//
#include <hip/hip_runtime.h>
#include <stdint.h>

// SNN audio classifier. 512 blocks x 512 threads, 1 sample/block, 8 waves,
// T=100 in-kernel. Round 11: round-10's verified 8-wave arithmetic, but
// 512-thread blocks (VGPR budget 128, not 64) and NO 90KB LDS weight store:
// fc1 weights read from global (L2-hot) inline in phase C, with an asm
// operand-copy preventing LICM from hoisting 44 regs of loop-invariant loads.
// LDS ~7.6KB -> 2 blocks/CU -> 16 waves/CU (4/SIMD).

#define NB 512
#define NT 100
#define LIN 686
#define RS 71          // spool2 row stride in v2f; cols 0,69,70 are zero pads

typedef float v2f __attribute__((ext_vector_type(2)));

__device__ __forceinline__ v2f pkfma(v2f a, v2f b, v2f c) {
    v2f d;
    asm("v_pk_fma_f32 %0, %1, %2, %3" : "=v"(d) : "v"(a), "v"(b), "v"(c));
    return d;
}

__device__ __forceinline__ float dpp_add8(float x) {   // sum over 8-lane groups
    int t;
    t = __builtin_amdgcn_mov_dpp(__float_as_int(x), 0x141, 0xf, 0xf, true); // row_half_mirror
    x += __int_as_float(t);
    t = __builtin_amdgcn_mov_dpp(__float_as_int(x), 0x1B, 0xf, 0xf, true);  // quad_perm [3,2,1,0]
    x += __int_as_float(t);
    t = __builtin_amdgcn_mov_dpp(__float_as_int(x), 0xB1, 0xf, 0xf, true);  // quad_perm [1,0,3,2]
    x += __int_as_float(t);
    return x;
}

__device__ __forceinline__ float red32(float x) {      // sum over 32-lane groups
    int t;
    t = __builtin_amdgcn_mov_dpp(__float_as_int(x), 0xB1, 0xf, 0xf, true);  // xor1
    x += __int_as_float(t);
    t = __builtin_amdgcn_mov_dpp(__float_as_int(x), 0x4E, 0xf, 0xf, true);  // xor2
    x += __int_as_float(t);
    t = __builtin_amdgcn_ds_swizzle(__float_as_int(x), 0x101F);             // xor4
    x += __int_as_float(t);
    t = __builtin_amdgcn_ds_swizzle(__float_as_int(x), 0x201F);             // xor8
    x += __int_as_float(t);
    t = __builtin_amdgcn_ds_swizzle(__float_as_int(x), 0x401F);             // xor16
    x += __int_as_float(t);
    return x;
}

__global__
__attribute__((amdgpu_flat_work_group_size(512, 512)))
void snn_all(
    const float* __restrict__ x,
    const float* __restrict__ w1, const float* __restrict__ b1,
    const float* __restrict__ w2, const float* __restrict__ b2,
    const float* __restrict__ wf1, const float* __restrict__ bf1,
    const float* __restrict__ wf2, const float* __restrict__ bf2,
    float* __restrict__ out)
{
    __shared__ __align__(16) float sx[LIN + 2];
    __shared__ __align__(16) float spool2f[8 * RS * 2];
    __shared__ unsigned long long sbits2[8][2];
    __shared__ __align__(8) float sspk3[32];

    const int t2   = threadIdx.x;      // 0..511
    const int b    = blockIdx.x;
    const int lane = t2 & 63;
    const int wv   = t2 >> 6;          // wave 0..7

    // ---- phase A setup: conv1. thread = (ca = t2&15, pg = t2>>4 in 0..31) ----
    const int ca = t2 & 15;
    const int pg = t2 >> 4;
    float wA[13];
    #pragma unroll
    for (int k = 0; k < 13; ++k) wA[k] = w1[ca * 13 + k];
    v2f we0 = {wA[0], wA[1]}, we1 = {wA[2], wA[3]}, we2 = {wA[4], wA[5]},
        we3 = {wA[6], wA[7]}, we4 = {wA[8], wA[9]}, we5 = {wA[10], wA[11]};
    v2f wo0 = {wA[1], wA[2]}, wo1 = {wA[3], wA[4]}, wo2 = {wA[5], wA[6]},
        wo3 = {wA[7], wA[8]}, wo4 = {wA[9], wA[10]}, wo5 = {wA[11], wA[12]};
    const float wA0s = wA[0], wA12s = wA[12];
    const float bA = b1[ca];
    float m1a[3], m1b[3];
    #pragma unroll
    for (int j = 0; j < 3; ++j) { m1a[j] = 0.f; m1b[j] = 0.f; }

    // ---- phase B setup: conv2. wave wv owns channel quartet 4wv..4wv+3 ----
    const int ip  = lane & 7;          // row-pair (conv1 rows 2ip, 2ip+1)
    const int og  = (lane >> 3) & 3;   // output phase
    const int omh = lane >> 5;         // window triple: om = {omh, 2+omh, 4+omh}
    const int ccq = ip & 3;            // owned channel within quartet
    v2f wp0[7], wp1[7], wp2[7], wp3[7];
    #pragma unroll
    for (int k = 0; k < 7; ++k) {
        int base0 = (wv * 4 + 0) * 112 + 14 * ip + k;
        int base1 = (wv * 4 + 1) * 112 + 14 * ip + k;
        int base2 = (wv * 4 + 2) * 112 + 14 * ip + k;
        int base3 = (wv * 4 + 3) * 112 + 14 * ip + k;
        wp0[k].x = w2[base0]; wp0[k].y = w2[base0 + 7];
        wp1[k].x = w2[base1]; wp1[k].y = w2[base1 + 7];
        wp2[k].x = w2[base2]; wp2[k].y = w2[base2 + 7];
        wp3[k].x = w2[base3]; wp3[k].y = w2[base3 + 7];
    }
    const float bB = b2[wv * 4 + ccq];
    float mA = 0.f, mB = 0.f;

    // ---- phase C setup: group gC = wv*2 + sub handles outputs 2gC, 2gC+1 ----
    const int sub = (t2 >> 5) & 1;
    const int gC  = wv * 2 + sub;
    const int s_  = t2 & 31;
    const float bC0 = bf1[2 * gC], bC1 = bf1[2 * gC + 1];
    float m30 = 0.f, m31 = 0.f;
    const int q_  = s_ >> 2;           // wave (quartet) holding channel s_
    const int cc_ = s_ & 3;            // channel within quartet
    const float* wgA = wf1 + (2 * gC) * 704 + s_ * 22;       // output 2gC row slice
    const float* wgB = wgA + 704;                            // output 2gC+1

    // ---- phase D setup: fc2 ----
    float wD = 0.f, bD = 0.f;
    if (t2 < 64) {
        wD = wf2[(t2 >> 5) * 32 + (t2 & 31)];
        if ((t2 & 31) == 0) bD = bf2[t2 >> 5];
    }
    float m4 = 0.f, cnt = 0.f;

    // ---- init LDS ----
    for (int i = t2; i < 8 * RS * 2; i += 512) spool2f[i] = 0.f;  // pads stay 0
    const float* xb = x + (size_t)b * NT * LIN;
    if (t2 == 0) { sx[0] = 0.f; sx[LIN + 1] = 0.f; }
    sx[1 + t2] = xb[t2];
    if (t2 < LIN - 512) sx[1 + t2 + 512] = xb[t2 + 512];
    __syncthreads();

    const v2f* spool2v = reinterpret_cast<const v2f*>(spool2f);
    const v2f* wb0 = spool2v + ip * RS + 3 * og + 12 * omh;        // window om=omh
    const v2f* wb1 = wb0 + 24;                                     // om = 2+omh
    const v2f* wb2 = wb0 + 48;                                     // om = 4+omh

// ===== phase A: conv1 (k13,s5,p1) + LIF1 + maxpool2; window = sx[10p .. 10p+17] =====
#define A_J(j) { \
    const int p_ = ((j) == 2) ? (64 + pg) : (pg + 32 * (j)); \
    if ((j) < 2 || pg < 4) { \
        const v2f* qv_ = reinterpret_cast<const v2f*>(sx + 10 * p_); \
        v2f q0_ = qv_[0], q1_ = qv_[1], q2_ = qv_[2], q3_ = qv_[3], q4_ = qv_[4], \
            q5_ = qv_[5], q6_ = qv_[6], q7_ = qv_[7], q8_ = qv_[8]; \
        v2f va_ = {0.f, 0.f}, vb_ = {0.f, 0.f}; \
        va_ = pkfma(we0, q0_, va_); va_ = pkfma(we1, q1_, va_); \
        va_ = pkfma(we2, q2_, va_); va_ = pkfma(we3, q3_, va_); \
        va_ = pkfma(we4, q4_, va_); va_ = pkfma(we5, q5_, va_); \
        vb_ = pkfma(wo0, q3_, vb_); vb_ = pkfma(wo1, q4_, vb_); \
        vb_ = pkfma(wo2, q5_, vb_); vb_ = pkfma(wo3, q6_, vb_); \
        vb_ = pkfma(wo4, q7_, vb_); vb_ = pkfma(wo5, q8_, vb_); \
        float a0_ = (va_.x + va_.y) + wA12s * q6_.x; \
        float a1_ = (vb_.x + vb_.y) + wA0s * q2_.y; \
        float m0_ = m1a[(j)], mm_ = m1b[(j)]; \
        float r0_ = (m0_ > 1.f) ? 1.f : 0.f; \
        float r1_ = (mm_ > 1.f) ? 1.f : 0.f; \
        m0_ = 0.9f * m0_ + (a0_ + bA) - r0_; \
        mm_ = 0.9f * mm_ + (a1_ + bA) - r1_; \
        m1a[(j)] = m0_; m1b[(j)] = mm_; \
        spool2f[((ca >> 1) * RS + 1 + p_) * 2 + (ca & 1)] = \
            (m0_ > 1.f || mm_ > 1.f) ? 1.f : 0.f; \
    } }

// ===== phase B window: 7 v2f taps, 4 channels, dpp reduce; owner per COND =====
#define B_WIN(WB, COND, MSLOT, SPK) { \
    v2f t0_ = (WB)[0], t1_ = (WB)[1], t2v_ = (WB)[2], t3_ = (WB)[3], \
        t4_ = (WB)[4], t5_ = (WB)[5], t6_ = (WB)[6]; \
    v2f a0_ = {0.f, 0.f}, a1_ = {0.f, 0.f}, a2_ = {0.f, 0.f}, a3_ = {0.f, 0.f}; \
    a0_ = pkfma(wp0[0], t0_, a0_); a1_ = pkfma(wp1[0], t0_, a1_); \
    a2_ = pkfma(wp2[0], t0_, a2_); a3_ = pkfma(wp3[0], t0_, a3_); \
    a0_ = pkfma(wp0[1], t1_, a0_); a1_ = pkfma(wp1[1], t1_, a1_); \
    a2_ = pkfma(wp2[1], t1_, a2_); a3_ = pkfma(wp3[1], t1_, a3_); \
    a0_ = pkfma(wp0[2], t2v_, a0_); a1_ = pkfma(wp1[2], t2v_, a1_); \
    a2_ = pkfma(wp2[2], t2v_, a2_); a3_ = pkfma(wp3[2], t2v_, a3_); \
    a0_ = pkfma(wp0[3], t3_, a0_); a1_ = pkfma(wp1[3], t3_, a1_); \
    a2_ = pkfma(wp2[3], t3_, a2_); a3_ = pkfma(wp3[3], t3_, a3_); \
    a0_ = pkfma(wp0[4], t4_, a0_); a1_ = pkfma(wp1[4], t4_, a1_); \
    a2_ = pkfma(wp2[4], t4_, a2_); a3_ = pkfma(wp3[4], t4_, a3_); \
    a0_ = pkfma(wp0[5], t5_, a0_); a1_ = pkfma(wp1[5], t5_, a1_); \
    a2_ = pkfma(wp2[5], t5_, a2_); a3_ = pkfma(wp3[5], t5_, a3_); \
    a0_ = pkfma(wp0[6], t6_, a0_); a1_ = pkfma(wp1[6], t6_, a1_); \
    a2_ = pkfma(wp2[6], t6_, a2_); a3_ = pkfma(wp3[6], t6_, a3_); \
    float s0_ = dpp_add8(a0_.x + a0_.y); \
    float s1_ = dpp_add8(a1_.x + a1_.y); \
    float s2_ = dpp_add8(a2_.x + a2_.y); \
    float s3_ = dpp_add8(a3_.x + a3_.y); \
    float sc_ = (ccq == 0) ? s0_ : ((ccq == 1) ? s1_ : ((ccq == 2) ? s2_ : s3_)); \
    if (COND) { \
        float mm_ = MSLOT; \
        float rr_ = (mm_ > 1.f) ? 1.f : 0.f; \
        mm_ = 0.9f * mm_ + (sc_ + bB) - rr_; \
        MSLOT = mm_; \
        SPK = (mm_ > 1.f) ? 1.f : 0.f; \
    } }

    for (int t = 0; t < NT; ++t) {
        // ===== phase A =====
        A_J(0) A_J(1) A_J(2)
        __syncthreads();   // bar1: spool2 ready; sx free to overwrite

        // ===== prefetch x(t+1) =====
        float xp0 = 0.f, xp1 = 0.f;
        if (t + 1 < NT) {
            const float* xt = xb + (size_t)(t + 1) * LIN;
            xp0 = xt[t2];
            if (t2 < LIN - 512) xp1 = xt[t2 + 512];
        }

        // ===== phase B: conv2 + LIF2; lane's windows om = {omh, 2+omh, 4+omh} =====
        float spkA = 0.f, spkB = 0.f;
        B_WIN(wb0, ip < 4,  mA, spkA)            // o = og + 4*omh        (o in 0..7)
        B_WIN(wb1, ip >= 4, mA, spkA)            // o = og + 8 + 4*omh    (o in 8..15)
        if (omh == 0 || og < 2) {
            B_WIN(wb2, ip < 4, mB, spkB)         // o = og + 16 + 4*omh   (o in 16..21)
        }

        // publish spikes
        {
            unsigned long long bal1 = __ballot(spkA > 0.5f);
            unsigned long long bal2 = __ballot(spkB > 0.5f);
            if (lane == 0) { sbits2[wv][0] = bal1; sbits2[wv][1] = bal2; }
        }

        // write x(t+1) (readers of sx are behind bar2+bar3)
        if (t + 1 < NT) {
            sx[1 + t2] = xp0;
            if (t2 < LIN - 512) sx[1 + t2 + 512] = xp1;
        }
        __syncthreads();   // bar2: sbits ready

        // ===== phase C: fc1 (704->32) + LIF3; weights streamed from L2 =====
        {
            unsigned long long Ms1 = sbits2[q_][0] >> cc_;
            unsigned long long Ms2 = sbits2[q_][1] >> cc_;
            uint32_t W1lo = (uint32_t)Ms1, W1hi = (uint32_t)(Ms1 >> 32);
            uint32_t W2lo = (uint32_t)Ms2, W2hi = (uint32_t)(Ms2 >> 32);

            // bit(o): o<16 -> W1[(o>>2)&1], shift 4*((o>>3)&1)+8*(o&3)
            //         o>=16 -> W2[(o>>2)&1], shift 8*(o&3)
            float f[22];
            #pragma unroll
            for (int o = 0; o < 22; ++o) {
                uint32_t w = (o < 16) ? (((o >> 2) & 1) ? W1hi : W1lo)
                                      : (((o >> 2) & 1) ? W2hi : W2lo);
                int sh = (o < 16) ? (4 * ((o >> 3) & 1) + 8 * (o & 3)) : (8 * (o & 3));
                f[o] = (float)((w >> sh) & 1u);
            }

            // anti-LICM: opaque per-iteration copies of the weight pointers so
            // the 22 loop-invariant b64 loads are NOT hoisted into 44 regs.
            const float* pA = wgA;
            const float* pB = wgB;
            asm volatile("" : "+v"(pA), "+v"(pB));

            v2f a0v = {0.f, 0.f}, a1v = {0.f, 0.f};
            #pragma unroll
            for (int i = 0; i < 11; ++i) {
                v2f fpi = (v2f){f[2 * i], f[2 * i + 1]};
                v2f u = *reinterpret_cast<const v2f*>(pA + 2 * i);
                v2f v = *reinterpret_cast<const v2f*>(pB + 2 * i);
                a0v = pkfma(u, fpi, a0v);
                a1v = pkfma(v, fpi, a1v);
            }
            float a0 = red32(a0v.x + a0v.y);
            float a1 = red32(a1v.x + a1v.y);

            float r0 = (m30 > 1.f) ? 1.f : 0.f; m30 = 0.9f * m30 + (a0 + bC0) - r0;
            float r1 = (m31 > 1.f) ? 1.f : 0.f; m31 = 0.9f * m31 + (a1 + bC1) - r1;
            if (s_ == 0) {
                float2 st;
                st.x = (m30 > 1.f) ? 1.f : 0.f;
                st.y = (m31 > 1.f) ? 1.f : 0.f;
                *reinterpret_cast<float2*>(&sspk3[2 * gC]) = st;
            }
        }
        __syncthreads();   // bar3: sspk3 ready

        // ===== phase D: fc2 (32->2) + LIF4 + count =====
        if (t2 < 64) {
            float v = sspk3[t2 & 31] * wD;
            v += __shfl_xor(v, 16, 32);
            v += __shfl_xor(v, 8, 32);
            v += __shfl_xor(v, 4, 32);
            v += __shfl_xor(v, 2, 32);
            v += __shfl_xor(v, 1, 32);
            if ((t2 & 31) == 0) {
                float rr = (m4 > 1.f) ? 1.f : 0.f;
                m4 = 0.9f * m4 + (v + bD) - rr;
                if (m4 > 1.f) cnt += 1.f;
            }
        }
        // no barrier: next writer of sspk3 (phase C of t+1) is behind bar1+bar2
    }

    if (t2 == 0)  out[b * 2 + 0] = cnt;
    if (t2 == 32) out[b * 2 + 1] = cnt;
}

extern "C" void kernel_launch(void* const* d_in, const int* in_sizes, int n_in,
                              void* d_out, int out_size, void* d_ws, size_t ws_size,
                              hipStream_t stream) {
    const float* x   = (const float*)d_in[0];
    const float* w1  = (const float*)d_in[1];
    const float* b1  = (const float*)d_in[2];
    const float* w2  = (const float*)d_in[3];
    const float* b2  = (const float*)d_in[4];
    const float* wf1 = (const float*)d_in[5];
    const float* bf1 = (const float*)d_in[6];
    const float* wf2 = (const float*)d_in[7];
    const float* bf2 = (const float*)d_in[8];
    float* out = (float*)d_out;

    snn_all<<<NB, 512, 0, stream>>>(x, w1, b1, w2, b2, wf1, bf1, wf2, bf2, out);
}

// Round 12
// 897.811 us; speedup vs baseline: 1.1985x; 1.1985x over previous
//
#include <hip/hip_runtime.h>
#include <stdint.h>

// SNN audio classifier. 256 blocks x 1024 threads, 2 samples/block (h = tid>>9),
// 8 waves per sample, T=100 in-kernel. Round 12: byte-identical body to round 10
// (verified correct, 45% occupancy) with __launch_bounds__(1024, 4): 4 waves/EU
// minimum -> per-wave VGPR budget 128 (round 10's default was 64 -> wholesale
// spills, FETCH 620MB/WRITE 133MB). Body demand ~90 VGPRs (round 11 measured 84).

#define NB 512
#define NT 100
#define LIN 686
#define RS 71          // spool2 row stride in v2f; cols 0,69,70 are zero pads

typedef float v2f __attribute__((ext_vector_type(2)));

__device__ __forceinline__ v2f pkfma(v2f a, v2f b, v2f c) {
    v2f d;
    asm("v_pk_fma_f32 %0, %1, %2, %3" : "=v"(d) : "v"(a), "v"(b), "v"(c));
    return d;
}

__device__ __forceinline__ float dpp_add8(float x) {   // sum over 8-lane groups
    int t;
    t = __builtin_amdgcn_mov_dpp(__float_as_int(x), 0x141, 0xf, 0xf, true); // row_half_mirror
    x += __int_as_float(t);
    t = __builtin_amdgcn_mov_dpp(__float_as_int(x), 0x1B, 0xf, 0xf, true);  // quad_perm [3,2,1,0]
    x += __int_as_float(t);
    t = __builtin_amdgcn_mov_dpp(__float_as_int(x), 0xB1, 0xf, 0xf, true);  // quad_perm [1,0,3,2]
    x += __int_as_float(t);
    return x;
}

__device__ __forceinline__ float red32(float x) {      // sum over 32-lane groups
    int t;
    t = __builtin_amdgcn_mov_dpp(__float_as_int(x), 0xB1, 0xf, 0xf, true);  // xor1
    x += __int_as_float(t);
    t = __builtin_amdgcn_mov_dpp(__float_as_int(x), 0x4E, 0xf, 0xf, true);  // xor2
    x += __int_as_float(t);
    t = __builtin_amdgcn_ds_swizzle(__float_as_int(x), 0x101F);             // xor4
    x += __int_as_float(t);
    t = __builtin_amdgcn_ds_swizzle(__float_as_int(x), 0x201F);             // xor8
    x += __int_as_float(t);
    t = __builtin_amdgcn_ds_swizzle(__float_as_int(x), 0x401F);             // xor16
    x += __int_as_float(t);
    return x;
}

__global__ __launch_bounds__(1024, 4) void snn_all(
    const float* __restrict__ x,
    const float* __restrict__ w1, const float* __restrict__ b1,
    const float* __restrict__ w2, const float* __restrict__ b2,
    const float* __restrict__ wf1, const float* __restrict__ bf1,
    const float* __restrict__ wf2, const float* __restrict__ bf2,
    float* __restrict__ out)
{
    // fc1 weights: f4[g*352 + i*32 + s] = {w[2g][s*22+2i], w[2g][s*22+2i+1],
    //                                      w[2g+1][s*22+2i], w[2g+1][s*22+2i+1]}
    // g in 0..15 (output pair), i in 0..10 (tap pair), s in 0..31 (channel).
    __shared__ __align__(16) float swf1r[5632 * 4];            // 90112 B, shared
    __shared__ __align__(16) float sx[2][LIN + 2];
    __shared__ __align__(16) float spool2f[2][8 * RS * 2];
    __shared__ unsigned long long sbits2[2][8][2];
    __shared__ __align__(8) float sspk3[2][32];

    const int tid  = threadIdx.x;
    const int h    = tid >> 9;
    const int t2   = tid & 511;
    const int b    = blockIdx.x * 2 + h;
    const int lane = t2 & 63;
    const int wv   = t2 >> 6;          // wave within the half: 0..7

    float* sxh    = sx[h];
    float* spoolh = spool2f[h];
    unsigned long long (*sbh)[2] = sbits2[h];
    float* sspk3h = sspk3[h];

    // ---------------- one-time init: reorder wf1 into LDS ----------------
    for (int d = tid; d < 5632; d += 1024) {
        int g = d / 352;
        int r = d - g * 352;
        int i = r >> 5;
        int s = r & 31;
        float4 v;
        v.x = wf1[(2 * g)     * 704 + s * 22 + 2 * i];
        v.y = wf1[(2 * g)     * 704 + s * 22 + 2 * i + 1];
        v.z = wf1[(2 * g + 1) * 704 + s * 22 + 2 * i];
        v.w = wf1[(2 * g + 1) * 704 + s * 22 + 2 * i + 1];
        reinterpret_cast<float4*>(swf1r)[d] = v;
    }

    // ---- phase A setup: conv1. thread = (ca = t2&15, pg = t2>>4 in 0..31) ----
    const int ca = t2 & 15;
    const int pg = t2 >> 4;
    float wA[13];
    #pragma unroll
    for (int k = 0; k < 13; ++k) wA[k] = w1[ca * 13 + k];
    v2f we0 = {wA[0], wA[1]}, we1 = {wA[2], wA[3]}, we2 = {wA[4], wA[5]},
        we3 = {wA[6], wA[7]}, we4 = {wA[8], wA[9]}, we5 = {wA[10], wA[11]};
    v2f wo0 = {wA[1], wA[2]}, wo1 = {wA[3], wA[4]}, wo2 = {wA[5], wA[6]},
        wo3 = {wA[7], wA[8]}, wo4 = {wA[9], wA[10]}, wo5 = {wA[11], wA[12]};
    const float wA0s = wA[0], wA12s = wA[12];
    const float bA = b1[ca];
    float m1a[3], m1b[3];
    #pragma unroll
    for (int j = 0; j < 3; ++j) { m1a[j] = 0.f; m1b[j] = 0.f; }

    // ---- phase B setup: conv2. wave wv owns channel quartet 4wv..4wv+3 ----
    const int ip  = lane & 7;          // row-pair (conv1 rows 2ip, 2ip+1)
    const int og  = (lane >> 3) & 3;   // output phase
    const int omh = lane >> 5;         // window triple: om = {omh, 2+omh, 4+omh}
    const int ccq = ip & 3;            // owned channel within quartet
    v2f wp0[7], wp1[7], wp2[7], wp3[7];
    #pragma unroll
    for (int k = 0; k < 7; ++k) {
        int base0 = (wv * 4 + 0) * 112 + 14 * ip + k;
        int base1 = (wv * 4 + 1) * 112 + 14 * ip + k;
        int base2 = (wv * 4 + 2) * 112 + 14 * ip + k;
        int base3 = (wv * 4 + 3) * 112 + 14 * ip + k;
        wp0[k].x = w2[base0]; wp0[k].y = w2[base0 + 7];
        wp1[k].x = w2[base1]; wp1[k].y = w2[base1 + 7];
        wp2[k].x = w2[base2]; wp2[k].y = w2[base2 + 7];
        wp3[k].x = w2[base3]; wp3[k].y = w2[base3 + 7];
    }
    const float bB = b2[wv * 4 + ccq];
    float mA = 0.f, mB = 0.f;

    // ---- phase C setup: group g = wv*2 + sub handles outputs 2g, 2g+1 ----
    const int sub = (t2 >> 5) & 1;
    const int gC  = wv * 2 + sub;
    const int s_  = t2 & 31;
    const float bC0 = bf1[2 * gC], bC1 = bf1[2 * gC + 1];
    float m30 = 0.f, m31 = 0.f;
    const int q_  = s_ >> 2;           // quartet (wave) holding channel s_
    const int cc_ = s_ & 3;            // channel within quartet

    // ---- phase D setup: fc2 ----
    float wD = 0.f, bD = 0.f;
    if (t2 < 64) {
        wD = wf2[(t2 >> 5) * 32 + (t2 & 31)];
        if ((t2 & 31) == 0) bD = bf2[t2 >> 5];
    }
    float m4 = 0.f, cnt = 0.f;

    // ---- init LDS (per half) ----
    for (int i = t2; i < 8 * RS * 2; i += 512) spoolh[i] = 0.f;  // pads stay 0
    const float* xb = x + (size_t)b * NT * LIN;
    if (t2 == 0) { sxh[0] = 0.f; sxh[LIN + 1] = 0.f; }
    sxh[1 + t2] = xb[t2];
    if (t2 < LIN - 512) sxh[1 + t2 + 512] = xb[t2 + 512];
    __syncthreads();

    const v2f* spool2v = reinterpret_cast<const v2f*>(spoolh);
    const v2f* wb0 = spool2v + ip * RS + 3 * og + 12 * omh;        // window om=omh
    const v2f* wb1 = wb0 + 24;                                     // om = 2+omh
    const v2f* wb2 = wb0 + 48;                                     // om = 4+omh
    const float4* wrow = reinterpret_cast<const float4*>(swf1r) + gC * 352 + s_;

// ===== phase A: conv1 (k13,s5,p1) + LIF1 + maxpool2; window = sx[10p .. 10p+17] =====
#define A_J(j) { \
    const int p_ = ((j) == 2) ? (64 + pg) : (pg + 32 * (j)); \
    if ((j) < 2 || pg < 4) { \
        const v2f* qv_ = reinterpret_cast<const v2f*>(sxh + 10 * p_); \
        v2f q0_ = qv_[0], q1_ = qv_[1], q2_ = qv_[2], q3_ = qv_[3], q4_ = qv_[4], \
            q5_ = qv_[5], q6_ = qv_[6], q7_ = qv_[7], q8_ = qv_[8]; \
        v2f va_ = {0.f, 0.f}, vb_ = {0.f, 0.f}; \
        va_ = pkfma(we0, q0_, va_); va_ = pkfma(we1, q1_, va_); \
        va_ = pkfma(we2, q2_, va_); va_ = pkfma(we3, q3_, va_); \
        va_ = pkfma(we4, q4_, va_); va_ = pkfma(we5, q5_, va_); \
        vb_ = pkfma(wo0, q3_, vb_); vb_ = pkfma(wo1, q4_, vb_); \
        vb_ = pkfma(wo2, q5_, vb_); vb_ = pkfma(wo3, q6_, vb_); \
        vb_ = pkfma(wo4, q7_, vb_); vb_ = pkfma(wo5, q8_, vb_); \
        float a0_ = (va_.x + va_.y) + wA12s * q6_.x; \
        float a1_ = (vb_.x + vb_.y) + wA0s * q2_.y; \
        float m0_ = m1a[(j)], mm_ = m1b[(j)]; \
        float r0_ = (m0_ > 1.f) ? 1.f : 0.f; \
        float r1_ = (mm_ > 1.f) ? 1.f : 0.f; \
        m0_ = 0.9f * m0_ + (a0_ + bA) - r0_; \
        mm_ = 0.9f * mm_ + (a1_ + bA) - r1_; \
        m1a[(j)] = m0_; m1b[(j)] = mm_; \
        spoolh[((ca >> 1) * RS + 1 + p_) * 2 + (ca & 1)] = \
            (m0_ > 1.f || mm_ > 1.f) ? 1.f : 0.f; \
    } }

// ===== phase B window: 7 v2f taps, 4 channels, dpp reduce; owner per COND =====
#define B_WIN(WB, COND, MSLOT, SPK) { \
    v2f t0_ = (WB)[0], t1_ = (WB)[1], t2v_ = (WB)[2], t3_ = (WB)[3], \
        t4_ = (WB)[4], t5_ = (WB)[5], t6_ = (WB)[6]; \
    v2f a0_ = {0.f, 0.f}, a1_ = {0.f, 0.f}, a2_ = {0.f, 0.f}, a3_ = {0.f, 0.f}; \
    a0_ = pkfma(wp0[0], t0_, a0_); a1_ = pkfma(wp1[0], t0_, a1_); \
    a2_ = pkfma(wp2[0], t0_, a2_); a3_ = pkfma(wp3[0], t0_, a3_); \
    a0_ = pkfma(wp0[1], t1_, a0_); a1_ = pkfma(wp1[1], t1_, a1_); \
    a2_ = pkfma(wp2[1], t1_, a2_); a3_ = pkfma(wp3[1], t1_, a3_); \
    a0_ = pkfma(wp0[2], t2v_, a0_); a1_ = pkfma(wp1[2], t2v_, a1_); \
    a2_ = pkfma(wp2[2], t2v_, a2_); a3_ = pkfma(wp3[2], t2v_, a3_); \
    a0_ = pkfma(wp0[3], t3_, a0_); a1_ = pkfma(wp1[3], t3_, a1_); \
    a2_ = pkfma(wp2[3], t3_, a2_); a3_ = pkfma(wp3[3], t3_, a3_); \
    a0_ = pkfma(wp0[4], t4_, a0_); a1_ = pkfma(wp1[4], t4_, a1_); \
    a2_ = pkfma(wp2[4], t4_, a2_); a3_ = pkfma(wp3[4], t4_, a3_); \
    a0_ = pkfma(wp0[5], t5_, a0_); a1_ = pkfma(wp1[5], t5_, a1_); \
    a2_ = pkfma(wp2[5], t5_, a2_); a3_ = pkfma(wp3[5], t5_, a3_); \
    a0_ = pkfma(wp0[6], t6_, a0_); a1_ = pkfma(wp1[6], t6_, a1_); \
    a2_ = pkfma(wp2[6], t6_, a2_); a3_ = pkfma(wp3[6], t6_, a3_); \
    float s0_ = dpp_add8(a0_.x + a0_.y); \
    float s1_ = dpp_add8(a1_.x + a1_.y); \
    float s2_ = dpp_add8(a2_.x + a2_.y); \
    float s3_ = dpp_add8(a3_.x + a3_.y); \
    float sc_ = (ccq == 0) ? s0_ : ((ccq == 1) ? s1_ : ((ccq == 2) ? s2_ : s3_)); \
    if (COND) { \
        float mm_ = MSLOT; \
        float rr_ = (mm_ > 1.f) ? 1.f : 0.f; \
        mm_ = 0.9f * mm_ + (sc_ + bB) - rr_; \
        MSLOT = mm_; \
        SPK = (mm_ > 1.f) ? 1.f : 0.f; \
    } }

    for (int t = 0; t < NT; ++t) {
        // ===== phase A =====
        A_J(0) A_J(1) A_J(2)
        __syncthreads();   // bar1: spool2 ready; sx free to overwrite

        // ===== prefetch x(t+1) =====
        float xp0 = 0.f, xp1 = 0.f;
        if (t + 1 < NT) {
            const float* xt = xb + (size_t)(t + 1) * LIN;
            xp0 = xt[t2];
            if (t2 < LIN - 512) xp1 = xt[t2 + 512];
        }

        // ===== phase B: conv2 + LIF2; lane's windows om = {omh, 2+omh, 4+omh} =====
        float spkA = 0.f, spkB = 0.f;
        B_WIN(wb0, ip < 4,  mA, spkA)            // o = og + 4*omh        (o in 0..7)
        B_WIN(wb1, ip >= 4, mA, spkA)            // o = og + 8 + 4*omh    (o in 8..15)
        if (omh == 0 || og < 2) {
            B_WIN(wb2, ip < 4, mB, spkB)         // o = og + 16 + 4*omh   (o in 16..21)
        }

        // publish spikes
        {
            unsigned long long bal1 = __ballot(spkA > 0.5f);
            unsigned long long bal2 = __ballot(spkB > 0.5f);
            if (lane == 0) { sbh[wv][0] = bal1; sbh[wv][1] = bal2; }
        }

        // write x(t+1) (readers of sx are behind bar2+bar3)
        if (t + 1 < NT) {
            sxh[1 + t2] = xp0;
            if (t2 < LIN - 512) sxh[1 + t2 + 512] = xp1;
        }
        __syncthreads();   // bar2: sbits ready

        // ===== phase C: fc1 (704->32) + LIF3; group gC -> outputs 2gC, 2gC+1 =====
        {
            unsigned long long Ms1 = sbh[q_][0] >> cc_;
            unsigned long long Ms2 = sbh[q_][1] >> cc_;
            uint32_t W1lo = (uint32_t)Ms1, W1hi = (uint32_t)(Ms1 >> 32);
            uint32_t W2lo = (uint32_t)Ms2, W2hi = (uint32_t)(Ms2 >> 32);

            // bit(o): o<16 -> W1[(o>>2)&1], shift 4*((o>>3)&1)+8*(o&3)
            //         o>=16 -> W2[(o>>2)&1], shift 8*(o&3)
            float f[22];
            #pragma unroll
            for (int o = 0; o < 22; ++o) {
                uint32_t w = (o < 16) ? (((o >> 2) & 1) ? W1hi : W1lo)
                                      : (((o >> 2) & 1) ? W2hi : W2lo);
                int sh = (o < 16) ? (4 * ((o >> 3) & 1) + 8 * (o & 3)) : (8 * (o & 3));
                f[o] = (float)((w >> sh) & 1u);
            }

            v2f a0v = {0.f, 0.f}, a1v = {0.f, 0.f};
            #pragma unroll
            for (int i = 0; i < 11; ++i) {
                v2f fpi = (v2f){f[2 * i], f[2 * i + 1]};
                float4 wa = wrow[i * 32];
                a0v = pkfma((v2f){wa.x, wa.y}, fpi, a0v);
                a1v = pkfma((v2f){wa.z, wa.w}, fpi, a1v);
            }
            float a0 = red32(a0v.x + a0v.y);
            float a1 = red32(a1v.x + a1v.y);

            float r0 = (m30 > 1.f) ? 1.f : 0.f; m30 = 0.9f * m30 + (a0 + bC0) - r0;
            float r1 = (m31 > 1.f) ? 1.f : 0.f; m31 = 0.9f * m31 + (a1 + bC1) - r1;
            if (s_ == 0) {
                float2 st;
                st.x = (m30 > 1.f) ? 1.f : 0.f;
                st.y = (m31 > 1.f) ? 1.f : 0.f;
                *reinterpret_cast<float2*>(&sspk3h[2 * gC]) = st;
            }
        }
        __syncthreads();   // bar3: sspk3 ready

        // ===== phase D: fc2 (32->2) + LIF4 + count =====
        if (t2 < 64) {
            float v = sspk3h[t2 & 31] * wD;
            v += __shfl_xor(v, 16, 32);
            v += __shfl_xor(v, 8, 32);
            v += __shfl_xor(v, 4, 32);
            v += __shfl_xor(v, 2, 32);
            v += __shfl_xor(v, 1, 32);
            if ((t2 & 31) == 0) {
                float rr = (m4 > 1.f) ? 1.f : 0.f;
                m4 = 0.9f * m4 + (v + bD) - rr;
                if (m4 > 1.f) cnt += 1.f;
            }
        }
        // no barrier: next writer of sspk3 (phase C of t+1) is behind bar1+bar2
    }

    if (t2 == 0)  out[b * 2 + 0] = cnt;
    if (t2 == 32) out[b * 2 + 1] = cnt;
}

extern "C" void kernel_launch(void* const* d_in, const int* in_sizes, int n_in,
                              void* d_out, int out_size, void* d_ws, size_t ws_size,
                              hipStream_t stream) {
    const float* x   = (const float*)d_in[0];
    const float* w1  = (const float*)d_in[1];
    const float* b1  = (const float*)d_in[2];
    const float* w2  = (const float*)d_in[3];
    const float* b2  = (const float*)d_in[4];
    const float* wf1 = (const float*)d_in[5];
    const float* bf1 = (const float*)d_in[6];
    const float* wf2 = (const float*)d_in[7];
    const float* bf2 = (const float*)d_in[8];
    float* out = (float*)d_out;

    snn_all<<<NB / 2, 1024, 0, stream>>>(x, w1, b1, w2, b2, wf1, bf1, wf2, bf2, out);
}

// Round 13
// 667.884 us; speedup vs baseline: 1.6111x; 1.3443x over previous
//
#include <hip/hip_runtime.h>
#include <stdint.h>

// SNN audio classifier. Round 13: 512 blocks x 512 threads, 1 sample/block,
// 8 waves (round-11 body, verified). Phase C fc1 weights from d_ws in a
// COALESCED reordered layout (pre-pass kernel), replacing round 11's
// uncoalesced per-lane slices. LDS ~7.6KB -> target 2 blocks/CU, 16 waves.

#define NB 512
#define NT 100
#define LIN 686
#define RS 71          // spool2 row stride in v2f; cols 0,69,70 are zero pads

typedef float v2f __attribute__((ext_vector_type(2)));

__device__ __forceinline__ v2f pkfma(v2f a, v2f b, v2f c) {
    v2f d;
    asm("v_pk_fma_f32 %0, %1, %2, %3" : "=v"(d) : "v"(a), "v"(b), "v"(c));
    return d;
}

__device__ __forceinline__ float dpp_add8(float x) {   // sum over 8-lane groups
    int t;
    t = __builtin_amdgcn_mov_dpp(__float_as_int(x), 0x141, 0xf, 0xf, true); // row_half_mirror
    x += __int_as_float(t);
    t = __builtin_amdgcn_mov_dpp(__float_as_int(x), 0x1B, 0xf, 0xf, true);  // quad_perm [3,2,1,0]
    x += __int_as_float(t);
    t = __builtin_amdgcn_mov_dpp(__float_as_int(x), 0xB1, 0xf, 0xf, true);  // quad_perm [1,0,3,2]
    x += __int_as_float(t);
    return x;
}

__device__ __forceinline__ float red32(float x) {      // sum over 32-lane groups
    int t;
    t = __builtin_amdgcn_mov_dpp(__float_as_int(x), 0xB1, 0xf, 0xf, true);  // xor1
    x += __int_as_float(t);
    t = __builtin_amdgcn_mov_dpp(__float_as_int(x), 0x4E, 0xf, 0xf, true);  // xor2
    x += __int_as_float(t);
    t = __builtin_amdgcn_ds_swizzle(__float_as_int(x), 0x101F);             // xor4
    x += __int_as_float(t);
    t = __builtin_amdgcn_ds_swizzle(__float_as_int(x), 0x201F);             // xor8
    x += __int_as_float(t);
    t = __builtin_amdgcn_ds_swizzle(__float_as_int(x), 0x401F);             // xor16
    x += __int_as_float(t);
    return x;
}

// ---- pre-pass: reorder wf1 into ws[g*352 + i*32 + s] (round-10-verified map) ----
__global__ __launch_bounds__(256) void reorder_wf1(
    const float* __restrict__ wf1, float4* __restrict__ ws)
{
    int d = blockIdx.x * 256 + threadIdx.x;
    if (d < 5632) {
        int g = d / 352;
        int r = d - g * 352;
        int i = r >> 5;
        int s = r & 31;
        float4 v;
        v.x = wf1[(2 * g)     * 704 + s * 22 + 2 * i];
        v.y = wf1[(2 * g)     * 704 + s * 22 + 2 * i + 1];
        v.z = wf1[(2 * g + 1) * 704 + s * 22 + 2 * i];
        v.w = wf1[(2 * g + 1) * 704 + s * 22 + 2 * i + 1];
        ws[d] = v;
    }
}

__global__
__attribute__((amdgpu_flat_work_group_size(512, 512)))
void snn_all(
    const float* __restrict__ x,
    const float* __restrict__ w1, const float* __restrict__ b1,
    const float* __restrict__ w2, const float* __restrict__ b2,
    const float4* __restrict__ wsr, const float* __restrict__ bf1,
    const float* __restrict__ wf2, const float* __restrict__ bf2,
    float* __restrict__ out)
{
    __shared__ __align__(16) float sx[LIN + 2];
    __shared__ __align__(16) float spool2f[8 * RS * 2];
    __shared__ unsigned long long sbits2[8][2];
    __shared__ __align__(8) float sspk3[32];

    const int t2   = threadIdx.x;      // 0..511
    const int b    = blockIdx.x;
    const int lane = t2 & 63;
    const int wv   = t2 >> 6;          // wave 0..7

    // ---- phase A setup: conv1. thread = (ca = t2&15, pg = t2>>4 in 0..31) ----
    const int ca = t2 & 15;
    const int pg = t2 >> 4;
    float wA[13];
    #pragma unroll
    for (int k = 0; k < 13; ++k) wA[k] = w1[ca * 13 + k];
    v2f we0 = {wA[0], wA[1]}, we1 = {wA[2], wA[3]}, we2 = {wA[4], wA[5]},
        we3 = {wA[6], wA[7]}, we4 = {wA[8], wA[9]}, we5 = {wA[10], wA[11]};
    v2f wo0 = {wA[1], wA[2]}, wo1 = {wA[3], wA[4]}, wo2 = {wA[5], wA[6]},
        wo3 = {wA[7], wA[8]}, wo4 = {wA[9], wA[10]}, wo5 = {wA[11], wA[12]};
    const float wA0s = wA[0], wA12s = wA[12];
    const float bA = b1[ca];
    float m1a[3], m1b[3];
    #pragma unroll
    for (int j = 0; j < 3; ++j) { m1a[j] = 0.f; m1b[j] = 0.f; }

    // ---- phase B setup: conv2. wave wv owns channel quartet 4wv..4wv+3 ----
    const int ip  = lane & 7;          // row-pair (conv1 rows 2ip, 2ip+1)
    const int og  = (lane >> 3) & 3;   // output phase
    const int omh = lane >> 5;         // window triple: om = {omh, 2+omh, 4+omh}
    const int ccq = ip & 3;            // owned channel within quartet
    v2f wp0[7], wp1[7], wp2[7], wp3[7];
    #pragma unroll
    for (int k = 0; k < 7; ++k) {
        int base0 = (wv * 4 + 0) * 112 + 14 * ip + k;
        int base1 = (wv * 4 + 1) * 112 + 14 * ip + k;
        int base2 = (wv * 4 + 2) * 112 + 14 * ip + k;
        int base3 = (wv * 4 + 3) * 112 + 14 * ip + k;
        wp0[k].x = w2[base0]; wp0[k].y = w2[base0 + 7];
        wp1[k].x = w2[base1]; wp1[k].y = w2[base1 + 7];
        wp2[k].x = w2[base2]; wp2[k].y = w2[base2 + 7];
        wp3[k].x = w2[base3]; wp3[k].y = w2[base3 + 7];
    }
    const float bB = b2[wv * 4 + ccq];
    float mA = 0.f, mB = 0.f;

    // ---- phase C setup: group gC = wv*2 + sub handles outputs 2gC, 2gC+1 ----
    const int sub = (t2 >> 5) & 1;
    const int gC  = wv * 2 + sub;
    const int s_  = t2 & 31;
    const float bC0 = bf1[2 * gC], bC1 = bf1[2 * gC + 1];
    float m30 = 0.f, m31 = 0.f;
    const int q_  = s_ >> 2;           // wave (quartet) holding channel s_
    const int cc_ = s_ & 3;            // channel within quartet
    const float4* wrowG = wsr + gC * 352 + s_;   // coalesced: lanes s_ -> consecutive f4

    // ---- phase D setup: fc2 ----
    float wD = 0.f, bD = 0.f;
    if (t2 < 64) {
        wD = wf2[(t2 >> 5) * 32 + (t2 & 31)];
        if ((t2 & 31) == 0) bD = bf2[t2 >> 5];
    }
    float m4 = 0.f, cnt = 0.f;

    // ---- init LDS ----
    for (int i = t2; i < 8 * RS * 2; i += 512) spool2f[i] = 0.f;  // pads stay 0
    const float* xb = x + (size_t)b * NT * LIN;
    if (t2 == 0) { sx[0] = 0.f; sx[LIN + 1] = 0.f; }
    sx[1 + t2] = xb[t2];
    if (t2 < LIN - 512) sx[1 + t2 + 512] = xb[t2 + 512];
    __syncthreads();

    const v2f* spool2v = reinterpret_cast<const v2f*>(spool2f);
    const v2f* wb0 = spool2v + ip * RS + 3 * og + 12 * omh;        // window om=omh
    const v2f* wb1 = wb0 + 24;                                     // om = 2+omh
    const v2f* wb2 = wb0 + 48;                                     // om = 4+omh

// ===== phase A: conv1 (k13,s5,p1) + LIF1 + maxpool2; window = sx[10p .. 10p+17] =====
#define A_J(j) { \
    const int p_ = ((j) == 2) ? (64 + pg) : (pg + 32 * (j)); \
    if ((j) < 2 || pg < 4) { \
        const v2f* qv_ = reinterpret_cast<const v2f*>(sx + 10 * p_); \
        v2f q0_ = qv_[0], q1_ = qv_[1], q2_ = qv_[2], q3_ = qv_[3], q4_ = qv_[4], \
            q5_ = qv_[5], q6_ = qv_[6], q7_ = qv_[7], q8_ = qv_[8]; \
        v2f va_ = {0.f, 0.f}, vb_ = {0.f, 0.f}; \
        va_ = pkfma(we0, q0_, va_); va_ = pkfma(we1, q1_, va_); \
        va_ = pkfma(we2, q2_, va_); va_ = pkfma(we3, q3_, va_); \
        va_ = pkfma(we4, q4_, va_); va_ = pkfma(we5, q5_, va_); \
        vb_ = pkfma(wo0, q3_, vb_); vb_ = pkfma(wo1, q4_, vb_); \
        vb_ = pkfma(wo2, q5_, vb_); vb_ = pkfma(wo3, q6_, vb_); \
        vb_ = pkfma(wo4, q7_, vb_); vb_ = pkfma(wo5, q8_, vb_); \
        float a0_ = (va_.x + va_.y) + wA12s * q6_.x; \
        float a1_ = (vb_.x + vb_.y) + wA0s * q2_.y; \
        float m0_ = m1a[(j)], mm_ = m1b[(j)]; \
        float r0_ = (m0_ > 1.f) ? 1.f : 0.f; \
        float r1_ = (mm_ > 1.f) ? 1.f : 0.f; \
        m0_ = 0.9f * m0_ + (a0_ + bA) - r0_; \
        mm_ = 0.9f * mm_ + (a1_ + bA) - r1_; \
        m1a[(j)] = m0_; m1b[(j)] = mm_; \
        spool2f[((ca >> 1) * RS + 1 + p_) * 2 + (ca & 1)] = \
            (m0_ > 1.f || mm_ > 1.f) ? 1.f : 0.f; \
    } }

// ===== phase B window: 7 v2f taps, 4 channels, dpp reduce; owner per COND =====
#define B_WIN(WB, COND, MSLOT, SPK) { \
    v2f t0_ = (WB)[0], t1_ = (WB)[1], t2v_ = (WB)[2], t3_ = (WB)[3], \
        t4_ = (WB)[4], t5_ = (WB)[5], t6_ = (WB)[6]; \
    v2f a0_ = {0.f, 0.f}, a1_ = {0.f, 0.f}, a2_ = {0.f, 0.f}, a3_ = {0.f, 0.f}; \
    a0_ = pkfma(wp0[0], t0_, a0_); a1_ = pkfma(wp1[0], t0_, a1_); \
    a2_ = pkfma(wp2[0], t0_, a2_); a3_ = pkfma(wp3[0], t0_, a3_); \
    a0_ = pkfma(wp0[1], t1_, a0_); a1_ = pkfma(wp1[1], t1_, a1_); \
    a2_ = pkfma(wp2[1], t1_, a2_); a3_ = pkfma(wp3[1], t1_, a3_); \
    a0_ = pkfma(wp0[2], t2v_, a0_); a1_ = pkfma(wp1[2], t2v_, a1_); \
    a2_ = pkfma(wp2[2], t2v_, a2_); a3_ = pkfma(wp3[2], t2v_, a3_); \
    a0_ = pkfma(wp0[3], t3_, a0_); a1_ = pkfma(wp1[3], t3_, a1_); \
    a2_ = pkfma(wp2[3], t3_, a2_); a3_ = pkfma(wp3[3], t3_, a3_); \
    a0_ = pkfma(wp0[4], t4_, a0_); a1_ = pkfma(wp1[4], t4_, a1_); \
    a2_ = pkfma(wp2[4], t4_, a2_); a3_ = pkfma(wp3[4], t4_, a3_); \
    a0_ = pkfma(wp0[5], t5_, a0_); a1_ = pkfma(wp1[5], t5_, a1_); \
    a2_ = pkfma(wp2[5], t5_, a2_); a3_ = pkfma(wp3[5], t5_, a3_); \
    a0_ = pkfma(wp0[6], t6_, a0_); a1_ = pkfma(wp1[6], t6_, a1_); \
    a2_ = pkfma(wp2[6], t6_, a2_); a3_ = pkfma(wp3[6], t6_, a3_); \
    float s0_ = dpp_add8(a0_.x + a0_.y); \
    float s1_ = dpp_add8(a1_.x + a1_.y); \
    float s2_ = dpp_add8(a2_.x + a2_.y); \
    float s3_ = dpp_add8(a3_.x + a3_.y); \
    float sc_ = (ccq == 0) ? s0_ : ((ccq == 1) ? s1_ : ((ccq == 2) ? s2_ : s3_)); \
    if (COND) { \
        float mm_ = MSLOT; \
        float rr_ = (mm_ > 1.f) ? 1.f : 0.f; \
        mm_ = 0.9f * mm_ + (sc_ + bB) - rr_; \
        MSLOT = mm_; \
        SPK = (mm_ > 1.f) ? 1.f : 0.f; \
    } }

    for (int t = 0; t < NT; ++t) {
        // ===== phase A =====
        A_J(0) A_J(1) A_J(2)
        __syncthreads();   // bar1: spool2 ready; sx free to overwrite

        // ===== prefetch x(t+1) =====
        float xp0 = 0.f, xp1 = 0.f;
        if (t + 1 < NT) {
            const float* xt = xb + (size_t)(t + 1) * LIN;
            xp0 = xt[t2];
            if (t2 < LIN - 512) xp1 = xt[t2 + 512];
        }

        // ===== phase B: conv2 + LIF2; lane's windows om = {omh, 2+omh, 4+omh} =====
        float spkA = 0.f, spkB = 0.f;
        B_WIN(wb0, ip < 4,  mA, spkA)            // o = og + 4*omh        (o in 0..7)
        B_WIN(wb1, ip >= 4, mA, spkA)            // o = og + 8 + 4*omh    (o in 8..15)
        if (omh == 0 || og < 2) {
            B_WIN(wb2, ip < 4, mB, spkB)         // o = og + 16 + 4*omh   (o in 16..21)
        }

        // publish spikes
        {
            unsigned long long bal1 = __ballot(spkA > 0.5f);
            unsigned long long bal2 = __ballot(spkB > 0.5f);
            if (lane == 0) { sbits2[wv][0] = bal1; sbits2[wv][1] = bal2; }
        }

        // write x(t+1) (readers of sx are behind bar2+bar3)
        if (t + 1 < NT) {
            sx[1 + t2] = xp0;
            if (t2 < LIN - 512) sx[1 + t2 + 512] = xp1;
        }
        __syncthreads();   // bar2: sbits ready

        // ===== phase C: fc1 (704->32) + LIF3; coalesced L2 weights =====
        {
            unsigned long long Ms1 = sbits2[q_][0] >> cc_;
            unsigned long long Ms2 = sbits2[q_][1] >> cc_;
            uint32_t W1lo = (uint32_t)Ms1, W1hi = (uint32_t)(Ms1 >> 32);
            uint32_t W2lo = (uint32_t)Ms2, W2hi = (uint32_t)(Ms2 >> 32);

            // bit(o): o<16 -> W1[(o>>2)&1], shift 4*((o>>3)&1)+8*(o&3)
            //         o>=16 -> W2[(o>>2)&1], shift 8*(o&3)
            float f[22];
            #pragma unroll
            for (int o = 0; o < 22; ++o) {
                uint32_t w = (o < 16) ? (((o >> 2) & 1) ? W1hi : W1lo)
                                      : (((o >> 2) & 1) ? W2hi : W2lo);
                int sh = (o < 16) ? (4 * ((o >> 3) & 1) + 8 * (o & 3)) : (8 * (o & 3));
                f[o] = (float)((w >> sh) & 1u);
            }

            // anti-LICM: opaque copy so the 11 loop-invariant b128 loads are
            // NOT hoisted into 44 persistent registers across the t-loop.
            const float4* pW = wrowG;
            asm volatile("" : "+v"(pW));

            v2f a0v = {0.f, 0.f}, a1v = {0.f, 0.f};
            #pragma unroll
            for (int i = 0; i < 11; ++i) {
                v2f fpi = (v2f){f[2 * i], f[2 * i + 1]};
                float4 wa = pW[i * 32];
                a0v = pkfma((v2f){wa.x, wa.y}, fpi, a0v);
                a1v = pkfma((v2f){wa.z, wa.w}, fpi, a1v);
            }
            float a0 = red32(a0v.x + a0v.y);
            float a1 = red32(a1v.x + a1v.y);

            float r0 = (m30 > 1.f) ? 1.f : 0.f; m30 = 0.9f * m30 + (a0 + bC0) - r0;
            float r1 = (m31 > 1.f) ? 1.f : 0.f; m31 = 0.9f * m31 + (a1 + bC1) - r1;
            if (s_ == 0) {
                float2 st;
                st.x = (m30 > 1.f) ? 1.f : 0.f;
                st.y = (m31 > 1.f) ? 1.f : 0.f;
                *reinterpret_cast<float2*>(&sspk3[2 * gC]) = st;
            }
        }
        __syncthreads();   // bar3: sspk3 ready

        // ===== phase D: fc2 (32->2) + LIF4 + count =====
        if (t2 < 64) {
            float v = sspk3[t2 & 31] * wD;
            v += __shfl_xor(v, 16, 32);
            v += __shfl_xor(v, 8, 32);
            v += __shfl_xor(v, 4, 32);
            v += __shfl_xor(v, 2, 32);
            v += __shfl_xor(v, 1, 32);
            if ((t2 & 31) == 0) {
                float rr = (m4 > 1.f) ? 1.f : 0.f;
                m4 = 0.9f * m4 + (v + bD) - rr;
                if (m4 > 1.f) cnt += 1.f;
            }
        }
        // no barrier: next writer of sspk3 (phase C of t+1) is behind bar1+bar2
    }

    if (t2 == 0)  out[b * 2 + 0] = cnt;
    if (t2 == 32) out[b * 2 + 1] = cnt;
}

extern "C" void kernel_launch(void* const* d_in, const int* in_sizes, int n_in,
                              void* d_out, int out_size, void* d_ws, size_t ws_size,
                              hipStream_t stream) {
    const float* x   = (const float*)d_in[0];
    const float* w1  = (const float*)d_in[1];
    const float* b1  = (const float*)d_in[2];
    const float* w2  = (const float*)d_in[3];
    const float* b2  = (const float*)d_in[4];
    const float* wf1 = (const float*)d_in[5];
    const float* bf1 = (const float*)d_in[6];
    const float* wf2 = (const float*)d_in[7];
    const float* bf2 = (const float*)d_in[8];
    float* out = (float*)d_out;
    float4* ws4 = (float4*)d_ws;

    reorder_wf1<<<22, 256, 0, stream>>>(wf1, ws4);
    snn_all<<<NB, 512, 0, stream>>>(x, w1, b1, w2, b2, ws4, bf1, wf2, bf2, out);
}

// Round 14
// 404.899 us; speedup vs baseline: 2.6575x; 1.6495x over previous
//
#include <hip/hip_runtime.h>
#include <stdint.h>

// SNN audio classifier. 256 blocks x 512 threads, 2 samples/block (h = tid>>8),
// T=100 in-kernel. Round 14: round-9 body (verified, 405us) with the loop
// re-skeletonized to 2 barriers/step: [B(t) | D(t-1) | x-prefetch] bar
// [A(t+1) | C(t)] bar. D deferred one interval (sspk3 stable across it).

#define NB 512
#define NT 100
#define LIN 686
#define RS 71          // spool2 row stride in v2f; cols 0,69,70 are zero pads

typedef float v2f __attribute__((ext_vector_type(2)));

__device__ __forceinline__ v2f pkfma(v2f a, v2f b, v2f c) {
    v2f d;
    asm("v_pk_fma_f32 %0, %1, %2, %3" : "=v"(d) : "v"(a), "v"(b), "v"(c));
    return d;
}

__device__ __forceinline__ float dpp_add8(float x) {   // sum over 8-lane groups
    int t;
    t = __builtin_amdgcn_mov_dpp(__float_as_int(x), 0x141, 0xf, 0xf, true); // row_half_mirror
    x += __int_as_float(t);
    t = __builtin_amdgcn_mov_dpp(__float_as_int(x), 0x1B, 0xf, 0xf, true);  // quad_perm [3,2,1,0]
    x += __int_as_float(t);
    t = __builtin_amdgcn_mov_dpp(__float_as_int(x), 0xB1, 0xf, 0xf, true);  // quad_perm [1,0,3,2]
    x += __int_as_float(t);
    return x;
}

__device__ __forceinline__ float red32(float x) {      // sum over 32-lane groups
    int t;
    t = __builtin_amdgcn_mov_dpp(__float_as_int(x), 0xB1, 0xf, 0xf, true);  // xor1
    x += __int_as_float(t);
    t = __builtin_amdgcn_mov_dpp(__float_as_int(x), 0x4E, 0xf, 0xf, true);  // xor2
    x += __int_as_float(t);
    t = __builtin_amdgcn_ds_swizzle(__float_as_int(x), 0x101F);             // xor4
    x += __int_as_float(t);
    t = __builtin_amdgcn_ds_swizzle(__float_as_int(x), 0x201F);             // xor8
    x += __int_as_float(t);
    t = __builtin_amdgcn_ds_swizzle(__float_as_int(x), 0x401F);             // xor16
    x += __int_as_float(t);
    return x;
}

__global__
__attribute__((amdgpu_flat_work_group_size(512, 512)))
__attribute__((amdgpu_waves_per_eu(1, 2)))
void snn_all(
    const float* __restrict__ x,
    const float* __restrict__ w1, const float* __restrict__ b1,
    const float* __restrict__ w2, const float* __restrict__ b2,
    const float* __restrict__ wf1, const float* __restrict__ bf1,
    const float* __restrict__ wf2, const float* __restrict__ bf2,
    float* __restrict__ out)
{
    // fc1 weights, reordered: f4[(wv*22 + i)*64 + lane]; i<11 -> {wj0p,wj1p},
    // i>=11 -> {wj2p,wj3p} for pair index i-11. Shared by both halves.
    __shared__ __align__(16) float swf1r[5632 * 4];            // 90112 B
    __shared__ __align__(16) float sx[2][LIN + 2];
    __shared__ __align__(16) float spool2f[2][8 * RS * 2];
    __shared__ unsigned long long sbits[2][4][3];
    __shared__ __align__(16) float sspk3[2][32];

    const int tid  = threadIdx.x;
    const int h    = tid >> 8;
    const int t2   = tid & 255;
    const int b    = blockIdx.x * 2 + h;
    const int lane = t2 & 63;
    const int wv   = t2 >> 6;          // wave within the half: 0..3

    float* sxh    = sx[h];
    float* spoolh = spool2f[h];
    unsigned long long (*sbh)[3] = sbits[h];
    float* sspk3h = sspk3[h];

    // ---------------- one-time init: reorder wf1 into LDS ----------------
    for (int d = tid; d < 5632; d += 512) {
        int wvd = d / 1408;            // 1408 = 22*64
        int r   = d - wvd * 1408;
        int i   = r >> 6;
        int l   = r & 63;
        int gg  = (l >> 5) & 1;
        int s   = l & 31;
        int jb0 = wvd * 8 + gg * 4;
        int ii  = (i < 11) ? i : (i - 11);
        int j0  = (i < 11) ? jb0 : (jb0 + 2);
        float4 v;
        v.x = wf1[(j0 + 0) * 704 + s * 22 + 2 * ii];
        v.y = wf1[(j0 + 0) * 704 + s * 22 + 2 * ii + 1];
        v.z = wf1[(j0 + 1) * 704 + s * 22 + 2 * ii];
        v.w = wf1[(j0 + 1) * 704 + s * 22 + 2 * ii + 1];
        reinterpret_cast<float4*>(swf1r)[d] = v;
    }

    // ---- phase A setup: conv1. thread = (ca = t2&15, pg = t2>>4) ----
    const int ca = t2 & 15;
    const int pg = t2 >> 4;
    float wA[13];
    #pragma unroll
    for (int k = 0; k < 13; ++k) wA[k] = w1[ca * 13 + k];
    v2f we0 = {wA[0], wA[1]}, we1 = {wA[2], wA[3]}, we2 = {wA[4], wA[5]},
        we3 = {wA[6], wA[7]}, we4 = {wA[8], wA[9]}, we5 = {wA[10], wA[11]};
    v2f wo0 = {wA[1], wA[2]}, wo1 = {wA[3], wA[4]}, wo2 = {wA[5], wA[6]},
        wo3 = {wA[7], wA[8]}, wo4 = {wA[9], wA[10]}, wo5 = {wA[11], wA[12]};
    const float wA0s = wA[0], wA12s = wA[12];
    const float bA = b1[ca];
    float m1a[5], m1b[5];
    #pragma unroll
    for (int j = 0; j < 5; ++j) { m1a[j] = 0.f; m1b[j] = 0.f; }

    // ---- phase B setup: conv2. lane = (X = l>>3 -> cg,og ; ip = l&7) ----
    const int ip = lane & 7;           // row-pair (conv1 channel pair 2ip,2ip+1)
    const int X  = lane >> 3;
    const int og = X & 3;              // output phase: o = og + 4*om
    const int cg = X >> 2;             // channel-quartet within wave's octet
    const int ccq = ip & 3;            // owner's channel within quartet
    const int chO = wv * 8 + cg * 4 + ccq;   // owned channel
    v2f wp0[7], wp1[7], wp2[7], wp3[7];
    #pragma unroll
    for (int k = 0; k < 7; ++k) {
        int base0 = (wv * 8 + cg * 4 + 0) * 112 + 14 * ip + k;
        int base1 = (wv * 8 + cg * 4 + 1) * 112 + 14 * ip + k;
        int base2 = (wv * 8 + cg * 4 + 2) * 112 + 14 * ip + k;
        int base3 = (wv * 8 + cg * 4 + 3) * 112 + 14 * ip + k;
        wp0[k].x = w2[base0]; wp0[k].y = w2[base0 + 7];
        wp1[k].x = w2[base1]; wp1[k].y = w2[base1 + 7];
        wp2[k].x = w2[base2]; wp2[k].y = w2[base2 + 7];
        wp3[k].x = w2[base3]; wp3[k].y = w2[base3 + 7];
    }
    const float bB = b2[chO];
    float m2r0 = 0.f, m2r1 = 0.f, m2r2 = 0.f;

    // ---- phase C setup: fc1. lane = (jb = 4 outputs, s_ = channel) ----
    const int gg = (t2 >> 5) & 1;
    const int s_ = t2 & 31;
    const int jb = wv * 8 + gg * 4;
    float bC0 = bf1[jb], bC1 = bf1[jb + 1], bC2 = bf1[jb + 2], bC3 = bf1[jb + 3];
    float m30 = 0.f, m31 = 0.f, m32 = 0.f, m33 = 0.f;
    const int cbsh = ((s_ >> 2) & 1) * 32 + (s_ & 3);   // runtime bit base

    // ---- phase D setup: fc2 ----
    float wD = 0.f, bD = 0.f;
    if (t2 < 64) {
        wD = wf2[(t2 >> 5) * 32 + (t2 & 31)];
        if ((t2 & 31) == 0) bD = bf2[t2 >> 5];
    }
    float m4 = 0.f, cnt = 0.f;

    // ---- init LDS (per half) ----
    for (int i = t2; i < 8 * RS * 2; i += 256) spoolh[i] = 0.f;  // pads stay 0
    const float* xb = x + (size_t)b * NT * LIN;
    if (t2 == 0) { sxh[0] = 0.f; sxh[LIN + 1] = 0.f; }
    sxh[1 + t2]       = xb[t2];
    sxh[1 + t2 + 256] = xb[t2 + 256];
    if (t2 < LIN - 512) sxh[1 + t2 + 512] = xb[t2 + 512];
    __syncthreads();

    const v2f* spool2v = reinterpret_cast<const v2f*>(spoolh);
    const v2f* wb = spool2v + ip * RS + 3 * og;   // per-lane window base
    const float4* swfv = reinterpret_cast<const float4*>(swf1r);
    const float4* wrow = swfv + (wv * 22) * 64 + lane;

// ===== phase A: conv1 (k13,s5,p1) + LIF1 + maxpool2; window = sx[10p .. 10p+17] =====
#define A_J(j) { \
    const int p_ = ((j) == 4) ? (64 + pg) : (pg + 16 * (j)); \
    if ((j) < 4 || pg < 4) { \
        const v2f* qv_ = reinterpret_cast<const v2f*>(sxh + 10 * p_); \
        v2f q0_ = qv_[0], q1_ = qv_[1], q2_ = qv_[2], q3_ = qv_[3], q4_ = qv_[4], \
            q5_ = qv_[5], q6_ = qv_[6], q7_ = qv_[7], q8_ = qv_[8]; \
        v2f va_ = {0.f, 0.f}, vb_ = {0.f, 0.f}; \
        va_ = pkfma(we0, q0_, va_); va_ = pkfma(we1, q1_, va_); \
        va_ = pkfma(we2, q2_, va_); va_ = pkfma(we3, q3_, va_); \
        va_ = pkfma(we4, q4_, va_); va_ = pkfma(we5, q5_, va_); \
        vb_ = pkfma(wo0, q3_, vb_); vb_ = pkfma(wo1, q4_, vb_); \
        vb_ = pkfma(wo2, q5_, vb_); vb_ = pkfma(wo3, q6_, vb_); \
        vb_ = pkfma(wo4, q7_, vb_); vb_ = pkfma(wo5, q8_, vb_); \
        float a0_ = (va_.x + va_.y) + wA12s * q6_.x; \
        float a1_ = (vb_.x + vb_.y) + wA0s * q2_.y; \
        float m0_ = m1a[(j)], mm_ = m1b[(j)]; \
        float r0_ = (m0_ > 1.f) ? 1.f : 0.f; \
        float r1_ = (mm_ > 1.f) ? 1.f : 0.f; \
        m0_ = 0.9f * m0_ + (a0_ + bA) - r0_; \
        mm_ = 0.9f * mm_ + (a1_ + bA) - r1_; \
        m1a[(j)] = m0_; m1b[(j)] = mm_; \
        spoolh[((ca >> 1) * RS + 1 + p_) * 2 + (ca & 1)] = \
            (m0_ > 1.f || mm_ > 1.f) ? 1.f : 0.f; \
    } }

// ===== phase B window: o = og + 4*om; 7 v2f taps, 4 channels, dpp reduce, owner LIF =====
#define B_WIN(om, MSLOT, SPK) { \
    v2f t0_ = wb[(om) * 12 + 0], t1_ = wb[(om) * 12 + 1], t2v_ = wb[(om) * 12 + 2], \
        t3_ = wb[(om) * 12 + 3], t4_ = wb[(om) * 12 + 4], t5_ = wb[(om) * 12 + 5], \
        t6_ = wb[(om) * 12 + 6]; \
    v2f a0_ = {0.f, 0.f}, a1_ = {0.f, 0.f}, a2_ = {0.f, 0.f}, a3_ = {0.f, 0.f}; \
    a0_ = pkfma(wp0[0], t0_, a0_); a1_ = pkfma(wp1[0], t0_, a1_); \
    a2_ = pkfma(wp2[0], t0_, a2_); a3_ = pkfma(wp3[0], t0_, a3_); \
    a0_ = pkfma(wp0[1], t1_, a0_); a1_ = pkfma(wp1[1], t1_, a1_); \
    a2_ = pkfma(wp2[1], t1_, a2_); a3_ = pkfma(wp3[1], t1_, a3_); \
    a0_ = pkfma(wp0[2], t2v_, a0_); a1_ = pkfma(wp1[2], t2v_, a1_); \
    a2_ = pkfma(wp2[2], t2v_, a2_); a3_ = pkfma(wp3[2], t2v_, a3_); \
    a0_ = pkfma(wp0[3], t3_, a0_); a1_ = pkfma(wp1[3], t3_, a1_); \
    a2_ = pkfma(wp2[3], t3_, a2_); a3_ = pkfma(wp3[3], t3_, a3_); \
    a0_ = pkfma(wp0[4], t4_, a0_); a1_ = pkfma(wp1[4], t4_, a1_); \
    a2_ = pkfma(wp2[4], t4_, a2_); a3_ = pkfma(wp3[4], t4_, a3_); \
    a0_ = pkfma(wp0[5], t5_, a0_); a1_ = pkfma(wp1[5], t5_, a1_); \
    a2_ = pkfma(wp2[5], t5_, a2_); a3_ = pkfma(wp3[5], t5_, a3_); \
    a0_ = pkfma(wp0[6], t6_, a0_); a1_ = pkfma(wp1[6], t6_, a1_); \
    a2_ = pkfma(wp2[6], t6_, a2_); a3_ = pkfma(wp3[6], t6_, a3_); \
    float s0_ = dpp_add8(a0_.x + a0_.y); \
    float s1_ = dpp_add8(a1_.x + a1_.y); \
    float s2_ = dpp_add8(a2_.x + a2_.y); \
    float s3_ = dpp_add8(a3_.x + a3_.y); \
    float sc_ = (ccq == 0) ? s0_ : ((ccq == 1) ? s1_ : ((ccq == 2) ? s2_ : s3_)); \
    if ((ip >> 2) == ((om) & 1)) { \
        float mm_ = MSLOT; \
        float rr_ = (mm_ > 1.f) ? 1.f : 0.f; \
        mm_ = 0.9f * mm_ + (sc_ + bB) - rr_; \
        MSLOT = mm_; \
        SPK = (mm_ > 1.f) ? 1.f : 0.f; \
    } }

// ===== phase D: fc2 (32->2) + LIF4 + count (reads sspk3 only) =====
#define PHASE_D() { \
    if (t2 < 64) { \
        float v = sspk3h[t2 & 31] * wD; \
        v += __shfl_xor(v, 16, 32); \
        v += __shfl_xor(v, 8, 32); \
        v += __shfl_xor(v, 4, 32); \
        v += __shfl_xor(v, 2, 32); \
        v += __shfl_xor(v, 1, 32); \
        if ((t2 & 31) == 0) { \
            float rr = (m4 > 1.f) ? 1.f : 0.f; \
            m4 = 0.9f * m4 + (v + bD) - rr; \
            if (m4 > 1.f) cnt += 1.f; \
        } \
    } }

    // ---- prologue: A(0) ----
    A_J(0) A_J(1) A_J(2) A_J(3) A_J(4)
    __syncthreads();   // spool(0) ready

    for (int t = 0; t < NT; ++t) {
        // ===== interval I2: B(t) | D(t-1) | x(t+1) prefetch =====
        float xp0 = 0.f, xp1 = 0.f, xp2 = 0.f;
        if (t + 1 < NT) {
            const float* xt = xb + (size_t)(t + 1) * LIN;
            xp0 = xt[t2];
            xp1 = xt[t2 + 256];
            if (t2 < LIN - 512) xp2 = xt[t2 + 512];
        }

        float spk0 = 0.f, spk1 = 0.f, spk2 = 0.f;
        B_WIN(0, m2r0, spk0)
        B_WIN(1, m2r0, spk0)
        B_WIN(2, m2r1, spk1)
        B_WIN(3, m2r1, spk1)
        B_WIN(4, m2r2, spk2)
        if (og < 2) { B_WIN(5, m2r2, spk2) }

        if (t > 0) { PHASE_D() }   // D(t-1): sspk3 stable until C(t) next interval

        // publish spikes as bits
        {
            unsigned long long bal0 = __ballot(spk0 > 0.5f);
            unsigned long long bal1 = __ballot(spk1 > 0.5f);
            unsigned long long bal2 = __ballot(spk2 > 0.5f);
            if (lane == 0) {
                sbh[wv][0] = bal0;
                sbh[wv][1] = bal1;
                sbh[wv][2] = bal2;
            }
        }

        // write x(t+1) (sx last read by A(t), which is behind the previous barrier)
        if (t + 1 < NT) {
            sxh[1 + t2]       = xp0;
            sxh[1 + t2 + 256] = xp1;
            if (t2 < LIN - 512) sxh[1 + t2 + 512] = xp2;
        }
        __syncthreads();   // sbits(t) ready; spool(t) consumed; sx(t+1) ready

        // ===== interval I1: A(t+1) | C(t) =====
        if (t + 1 < NT) {
            A_J(0) A_J(1) A_J(2) A_J(3) A_J(4)   // writes spool(t+1)
        }

        {
            unsigned long long M0 = sbh[s_ >> 3][0];
            unsigned long long M1 = sbh[s_ >> 3][1];
            unsigned long long M2 = sbh[s_ >> 3][2];
            uint32_t W0 = (uint32_t)(M0 >> cbsh);
            uint32_t W1 = (uint32_t)(M1 >> cbsh);
            uint32_t W2 = (uint32_t)(M2 >> cbsh);

            v2f a0v = {0.f, 0.f}, a1v = {0.f, 0.f}, a2v = {0.f, 0.f}, a3v = {0.f, 0.f};
            #pragma unroll
            for (int i = 0; i < 11; ++i) {
                const int o0 = 2 * i, o1 = 2 * i + 1;
                uint32_t wl0 = (o0 < 8) ? W0 : ((o0 < 16) ? W1 : W2);
                uint32_t wl1 = (o1 < 8) ? W0 : ((o1 < 16) ? W1 : W2);
                v2f fpi;
                fpi.x = (float)((wl0 >> ((o0 & 3) * 8 + ((o0 >> 2) & 1) * 4)) & 1u);
                fpi.y = (float)((wl1 >> ((o1 & 3) * 8 + ((o1 >> 2) & 1) * 4)) & 1u);
                float4 wa  = wrow[i * 64];          // {wj0p, wj1p}
                float4 wb4 = wrow[(11 + i) * 64];   // {wj2p, wj3p}
                a0v = pkfma((v2f){wa.x,  wa.y},  fpi, a0v);
                a1v = pkfma((v2f){wa.z,  wa.w},  fpi, a1v);
                a2v = pkfma((v2f){wb4.x, wb4.y}, fpi, a2v);
                a3v = pkfma((v2f){wb4.z, wb4.w}, fpi, a3v);
            }
            float a0 = red32(a0v.x + a0v.y);
            float a1 = red32(a1v.x + a1v.y);
            float a2 = red32(a2v.x + a2v.y);
            float a3 = red32(a3v.x + a3v.y);

            float r0 = (m30 > 1.f) ? 1.f : 0.f; m30 = 0.9f * m30 + (a0 + bC0) - r0;
            float r1 = (m31 > 1.f) ? 1.f : 0.f; m31 = 0.9f * m31 + (a1 + bC1) - r1;
            float r2 = (m32 > 1.f) ? 1.f : 0.f; m32 = 0.9f * m32 + (a2 + bC2) - r2;
            float r3 = (m33 > 1.f) ? 1.f : 0.f; m33 = 0.9f * m33 + (a3 + bC3) - r3;
            if (s_ == 0) {
                float4 st;
                st.x = (m30 > 1.f) ? 1.f : 0.f;
                st.y = (m31 > 1.f) ? 1.f : 0.f;
                st.z = (m32 > 1.f) ? 1.f : 0.f;
                st.w = (m33 > 1.f) ? 1.f : 0.f;
                *reinterpret_cast<float4*>(&sspk3h[jb]) = st;
            }
        }
        __syncthreads();   // sspk3(t) ready for D in next I2; spool(t+1) ready for B
    }

    // ---- epilogue: D(NT-1) ----
    PHASE_D()

    if (t2 == 0)  out[b * 2 + 0] = cnt;
    if (t2 == 32) out[b * 2 + 1] = cnt;
}

extern "C" void kernel_launch(void* const* d_in, const int* in_sizes, int n_in,
                              void* d_out, int out_size, void* d_ws, size_t ws_size,
                              hipStream_t stream) {
    const float* x   = (const float*)d_in[0];
    const float* w1  = (const float*)d_in[1];
    const float* b1  = (const float*)d_in[2];
    const float* w2  = (const float*)d_in[3];
    const float* b2  = (const float*)d_in[4];
    const float* wf1 = (const float*)d_in[5];
    const float* bf1 = (const float*)d_in[6];
    const float* wf2 = (const float*)d_in[7];
    const float* bf2 = (const float*)d_in[8];
    float* out = (float*)d_out;

    snn_all<<<NB / 2, 512, 0, stream>>>(x, w1, b1, w2, b2, wf1, bf1, wf2, bf2, out);
}

// Round 15
// 379.069 us; speedup vs baseline: 2.8386x; 1.0681x over previous
//
#include <hip/hip_runtime.h>
#include <stdint.h>

// SNN audio classifier. 256 blocks x 512 threads, 2 samples/block (h = tid>>8),
// T=100 in-kernel. Round 15 = round 14 body with two targeted fixes:
//  (1) spool row stride RS 71 -> 82 (RS mod 16 == 2): phase-B b64 reads tile
//      all 32 LDS banks exactly 2x -> zero conflict cycles (was ~3-way).
//  (2) red32 via DPP row_ror:4/8 rotation-adds: 1 ds_swizzle per reduce
//      instead of 3 (DS-pipe ops 12 -> 4 per lane-step, shorter DS chain).

#define NB 512
#define NT 100
#define LIN 686
#define RS 82          // spool2 row stride in v2f; cols 0,69..81 are zero pads

typedef float v2f __attribute__((ext_vector_type(2)));

__device__ __forceinline__ v2f pkfma(v2f a, v2f b, v2f c) {
    v2f d;
    asm("v_pk_fma_f32 %0, %1, %2, %3" : "=v"(d) : "v"(a), "v"(b), "v"(c));
    return d;
}

__device__ __forceinline__ float dpp_add8(float x) {   // sum over 8-lane groups
    int t;
    t = __builtin_amdgcn_mov_dpp(__float_as_int(x), 0x141, 0xf, 0xf, true); // row_half_mirror
    x += __int_as_float(t);
    t = __builtin_amdgcn_mov_dpp(__float_as_int(x), 0x1B, 0xf, 0xf, true);  // quad_perm [3,2,1,0]
    x += __int_as_float(t);
    t = __builtin_amdgcn_mov_dpp(__float_as_int(x), 0xB1, 0xf, 0xf, true);  // quad_perm [1,0,3,2]
    x += __int_as_float(t);
    return x;
}

__device__ __forceinline__ float red32(float x) {      // sum over 32-lane groups
    int t;
    t = __builtin_amdgcn_mov_dpp(__float_as_int(x), 0xB1, 0xf, 0xf, true);  // xor1 (quad)
    x += __int_as_float(t);
    t = __builtin_amdgcn_mov_dpp(__float_as_int(x), 0x4E, 0xf, 0xf, true);  // xor2 (quad)
    x += __int_as_float(t);
    t = __builtin_amdgcn_mov_dpp(__float_as_int(x), 0x124, 0xf, 0xf, true); // row_ror:4
    x += __int_as_float(t);                                                 // -> 8-grp pair sums
    t = __builtin_amdgcn_mov_dpp(__float_as_int(x), 0x128, 0xf, 0xf, true); // row_ror:8
    x += __int_as_float(t);                                                 // -> 16-row sums
    t = __builtin_amdgcn_ds_swizzle(__float_as_int(x), 0x401F);             // xor16 (32-grp)
    x += __int_as_float(t);
    return x;
}

__global__
__attribute__((amdgpu_flat_work_group_size(512, 512)))
__attribute__((amdgpu_waves_per_eu(1, 2)))
void snn_all(
    const float* __restrict__ x,
    const float* __restrict__ w1, const float* __restrict__ b1,
    const float* __restrict__ w2, const float* __restrict__ b2,
    const float* __restrict__ wf1, const float* __restrict__ bf1,
    const float* __restrict__ wf2, const float* __restrict__ bf2,
    float* __restrict__ out)
{
    // fc1 weights, reordered: f4[(wv*22 + i)*64 + lane]; i<11 -> {wj0p,wj1p},
    // i>=11 -> {wj2p,wj3p} for pair index i-11. Shared by both halves.
    __shared__ __align__(16) float swf1r[5632 * 4];            // 90112 B
    __shared__ __align__(16) float sx[2][LIN + 2];
    __shared__ __align__(16) float spool2f[2][8 * RS * 2];
    __shared__ unsigned long long sbits[2][4][3];
    __shared__ __align__(16) float sspk3[2][32];

    const int tid  = threadIdx.x;
    const int h    = tid >> 8;
    const int t2   = tid & 255;
    const int b    = blockIdx.x * 2 + h;
    const int lane = t2 & 63;
    const int wv   = t2 >> 6;          // wave within the half: 0..3

    float* sxh    = sx[h];
    float* spoolh = spool2f[h];
    unsigned long long (*sbh)[3] = sbits[h];
    float* sspk3h = sspk3[h];

    // ---------------- one-time init: reorder wf1 into LDS ----------------
    for (int d = tid; d < 5632; d += 512) {
        int wvd = d / 1408;            // 1408 = 22*64
        int r   = d - wvd * 1408;
        int i   = r >> 6;
        int l   = r & 63;
        int gg  = (l >> 5) & 1;
        int s   = l & 31;
        int jb0 = wvd * 8 + gg * 4;
        int ii  = (i < 11) ? i : (i - 11);
        int j0  = (i < 11) ? jb0 : (jb0 + 2);
        float4 v;
        v.x = wf1[(j0 + 0) * 704 + s * 22 + 2 * ii];
        v.y = wf1[(j0 + 0) * 704 + s * 22 + 2 * ii + 1];
        v.z = wf1[(j0 + 1) * 704 + s * 22 + 2 * ii];
        v.w = wf1[(j0 + 1) * 704 + s * 22 + 2 * ii + 1];
        reinterpret_cast<float4*>(swf1r)[d] = v;
    }

    // ---- phase A setup: conv1. thread = (ca = t2&15, pg = t2>>4) ----
    const int ca = t2 & 15;
    const int pg = t2 >> 4;
    float wA[13];
    #pragma unroll
    for (int k = 0; k < 13; ++k) wA[k] = w1[ca * 13 + k];
    v2f we0 = {wA[0], wA[1]}, we1 = {wA[2], wA[3]}, we2 = {wA[4], wA[5]},
        we3 = {wA[6], wA[7]}, we4 = {wA[8], wA[9]}, we5 = {wA[10], wA[11]};
    v2f wo0 = {wA[1], wA[2]}, wo1 = {wA[3], wA[4]}, wo2 = {wA[5], wA[6]},
        wo3 = {wA[7], wA[8]}, wo4 = {wA[9], wA[10]}, wo5 = {wA[11], wA[12]};
    const float wA0s = wA[0], wA12s = wA[12];
    const float bA = b1[ca];
    float m1a[5], m1b[5];
    #pragma unroll
    for (int j = 0; j < 5; ++j) { m1a[j] = 0.f; m1b[j] = 0.f; }

    // ---- phase B setup: conv2. lane = (X = l>>3 -> cg,og ; ip = l&7) ----
    const int ip = lane & 7;           // row-pair (conv1 channel pair 2ip,2ip+1)
    const int X  = lane >> 3;
    const int og = X & 3;              // output phase: o = og + 4*om
    const int cg = X >> 2;             // channel-quartet within wave's octet
    const int ccq = ip & 3;            // owner's channel within quartet
    const int chO = wv * 8 + cg * 4 + ccq;   // owned channel
    v2f wp0[7], wp1[7], wp2[7], wp3[7];
    #pragma unroll
    for (int k = 0; k < 7; ++k) {
        int base0 = (wv * 8 + cg * 4 + 0) * 112 + 14 * ip + k;
        int base1 = (wv * 8 + cg * 4 + 1) * 112 + 14 * ip + k;
        int base2 = (wv * 8 + cg * 4 + 2) * 112 + 14 * ip + k;
        int base3 = (wv * 8 + cg * 4 + 3) * 112 + 14 * ip + k;
        wp0[k].x = w2[base0]; wp0[k].y = w2[base0 + 7];
        wp1[k].x = w2[base1]; wp1[k].y = w2[base1 + 7];
        wp2[k].x = w2[base2]; wp2[k].y = w2[base2 + 7];
        wp3[k].x = w2[base3]; wp3[k].y = w2[base3 + 7];
    }
    const float bB = b2[chO];
    float m2r0 = 0.f, m2r1 = 0.f, m2r2 = 0.f;

    // ---- phase C setup: fc1. lane = (jb = 4 outputs, s_ = channel) ----
    const int gg = (t2 >> 5) & 1;
    const int s_ = t2 & 31;
    const int jb = wv * 8 + gg * 4;
    float bC0 = bf1[jb], bC1 = bf1[jb + 1], bC2 = bf1[jb + 2], bC3 = bf1[jb + 3];
    float m30 = 0.f, m31 = 0.f, m32 = 0.f, m33 = 0.f;
    const int cbsh = ((s_ >> 2) & 1) * 32 + (s_ & 3);   // runtime bit base

    // ---- phase D setup: fc2 ----
    float wD = 0.f, bD = 0.f;
    if (t2 < 64) {
        wD = wf2[(t2 >> 5) * 32 + (t2 & 31)];
        if ((t2 & 31) == 0) bD = bf2[t2 >> 5];
    }
    float m4 = 0.f, cnt = 0.f;

    // ---- init LDS (per half) ----
    for (int i = t2; i < 8 * RS * 2; i += 256) spoolh[i] = 0.f;  // pads stay 0
    const float* xb = x + (size_t)b * NT * LIN;
    if (t2 == 0) { sxh[0] = 0.f; sxh[LIN + 1] = 0.f; }
    sxh[1 + t2]       = xb[t2];
    sxh[1 + t2 + 256] = xb[t2 + 256];
    if (t2 < LIN - 512) sxh[1 + t2 + 512] = xb[t2 + 512];
    __syncthreads();

    const v2f* spool2v = reinterpret_cast<const v2f*>(spoolh);
    const v2f* wb = spool2v + ip * RS + 3 * og;   // per-lane window base
    const float4* swfv = reinterpret_cast<const float4*>(swf1r);
    const float4* wrow = swfv + (wv * 22) * 64 + lane;

// ===== phase A: conv1 (k13,s5,p1) + LIF1 + maxpool2; window = sx[10p .. 10p+17] =====
#define A_J(j) { \
    const int p_ = ((j) == 4) ? (64 + pg) : (pg + 16 * (j)); \
    if ((j) < 4 || pg < 4) { \
        const v2f* qv_ = reinterpret_cast<const v2f*>(sxh + 10 * p_); \
        v2f q0_ = qv_[0], q1_ = qv_[1], q2_ = qv_[2], q3_ = qv_[3], q4_ = qv_[4], \
            q5_ = qv_[5], q6_ = qv_[6], q7_ = qv_[7], q8_ = qv_[8]; \
        v2f va_ = {0.f, 0.f}, vb_ = {0.f, 0.f}; \
        va_ = pkfma(we0, q0_, va_); va_ = pkfma(we1, q1_, va_); \
        va_ = pkfma(we2, q2_, va_); va_ = pkfma(we3, q3_, va_); \
        va_ = pkfma(we4, q4_, va_); va_ = pkfma(we5, q5_, va_); \
        vb_ = pkfma(wo0, q3_, vb_); vb_ = pkfma(wo1, q4_, vb_); \
        vb_ = pkfma(wo2, q5_, vb_); vb_ = pkfma(wo3, q6_, vb_); \
        vb_ = pkfma(wo4, q7_, vb_); vb_ = pkfma(wo5, q8_, vb_); \
        float a0_ = (va_.x + va_.y) + wA12s * q6_.x; \
        float a1_ = (vb_.x + vb_.y) + wA0s * q2_.y; \
        float m0_ = m1a[(j)], mm_ = m1b[(j)]; \
        float r0_ = (m0_ > 1.f) ? 1.f : 0.f; \
        float r1_ = (mm_ > 1.f) ? 1.f : 0.f; \
        m0_ = 0.9f * m0_ + (a0_ + bA) - r0_; \
        mm_ = 0.9f * mm_ + (a1_ + bA) - r1_; \
        m1a[(j)] = m0_; m1b[(j)] = mm_; \
        spoolh[((ca >> 1) * RS + 1 + p_) * 2 + (ca & 1)] = \
            (m0_ > 1.f || mm_ > 1.f) ? 1.f : 0.f; \
    } }

// ===== phase B window: o = og + 4*om; 7 v2f taps, 4 channels, dpp reduce, owner LIF =====
#define B_WIN(om, MSLOT, SPK) { \
    v2f t0_ = wb[(om) * 12 + 0], t1_ = wb[(om) * 12 + 1], t2v_ = wb[(om) * 12 + 2], \
        t3_ = wb[(om) * 12 + 3], t4_ = wb[(om) * 12 + 4], t5_ = wb[(om) * 12 + 5], \
        t6_ = wb[(om) * 12 + 6]; \
    v2f a0_ = {0.f, 0.f}, a1_ = {0.f, 0.f}, a2_ = {0.f, 0.f}, a3_ = {0.f, 0.f}; \
    a0_ = pkfma(wp0[0], t0_, a0_); a1_ = pkfma(wp1[0], t0_, a1_); \
    a2_ = pkfma(wp2[0], t0_, a2_); a3_ = pkfma(wp3[0], t0_, a3_); \
    a0_ = pkfma(wp0[1], t1_, a0_); a1_ = pkfma(wp1[1], t1_, a1_); \
    a2_ = pkfma(wp2[1], t1_, a2_); a3_ = pkfma(wp3[1], t1_, a3_); \
    a0_ = pkfma(wp0[2], t2v_, a0_); a1_ = pkfma(wp1[2], t2v_, a1_); \
    a2_ = pkfma(wp2[2], t2v_, a2_); a3_ = pkfma(wp3[2], t2v_, a3_); \
    a0_ = pkfma(wp0[3], t3_, a0_); a1_ = pkfma(wp1[3], t3_, a1_); \
    a2_ = pkfma(wp2[3], t3_, a2_); a3_ = pkfma(wp3[3], t3_, a3_); \
    a0_ = pkfma(wp0[4], t4_, a0_); a1_ = pkfma(wp1[4], t4_, a1_); \
    a2_ = pkfma(wp2[4], t4_, a2_); a3_ = pkfma(wp3[4], t4_, a3_); \
    a0_ = pkfma(wp0[5], t5_, a0_); a1_ = pkfma(wp1[5], t5_, a1_); \
    a2_ = pkfma(wp2[5], t5_, a2_); a3_ = pkfma(wp3[5], t5_, a3_); \
    a0_ = pkfma(wp0[6], t6_, a0_); a1_ = pkfma(wp1[6], t6_, a1_); \
    a2_ = pkfma(wp2[6], t6_, a2_); a3_ = pkfma(wp3[6], t6_, a3_); \
    float s0_ = dpp_add8(a0_.x + a0_.y); \
    float s1_ = dpp_add8(a1_.x + a1_.y); \
    float s2_ = dpp_add8(a2_.x + a2_.y); \
    float s3_ = dpp_add8(a3_.x + a3_.y); \
    float sc_ = (ccq == 0) ? s0_ : ((ccq == 1) ? s1_ : ((ccq == 2) ? s2_ : s3_)); \
    if ((ip >> 2) == ((om) & 1)) { \
        float mm_ = MSLOT; \
        float rr_ = (mm_ > 1.f) ? 1.f : 0.f; \
        mm_ = 0.9f * mm_ + (sc_ + bB) - rr_; \
        MSLOT = mm_; \
        SPK = (mm_ > 1.f) ? 1.f : 0.f; \
    } }

// ===== phase D: fc2 (32->2) + LIF4 + count (reads sspk3 only) =====
#define PHASE_D() { \
    if (t2 < 64) { \
        float v = sspk3h[t2 & 31] * wD; \
        v += __shfl_xor(v, 16, 32); \
        v += __shfl_xor(v, 8, 32); \
        v += __shfl_xor(v, 4, 32); \
        v += __shfl_xor(v, 2, 32); \
        v += __shfl_xor(v, 1, 32); \
        if ((t2 & 31) == 0) { \
            float rr = (m4 > 1.f) ? 1.f : 0.f; \
            m4 = 0.9f * m4 + (v + bD) - rr; \
            if (m4 > 1.f) cnt += 1.f; \
        } \
    } }

    // ---- prologue: A(0) ----
    A_J(0) A_J(1) A_J(2) A_J(3) A_J(4)
    __syncthreads();   // spool(0) ready

    for (int t = 0; t < NT; ++t) {
        // ===== interval I2: B(t) | D(t-1) | x(t+1) prefetch =====
        float xp0 = 0.f, xp1 = 0.f, xp2 = 0.f;
        if (t + 1 < NT) {
            const float* xt = xb + (size_t)(t + 1) * LIN;
            xp0 = xt[t2];
            xp1 = xt[t2 + 256];
            if (t2 < LIN - 512) xp2 = xt[t2 + 512];
        }

        float spk0 = 0.f, spk1 = 0.f, spk2 = 0.f;
        B_WIN(0, m2r0, spk0)
        B_WIN(1, m2r0, spk0)
        B_WIN(2, m2r1, spk1)
        B_WIN(3, m2r1, spk1)
        B_WIN(4, m2r2, spk2)
        if (og < 2) { B_WIN(5, m2r2, spk2) }

        if (t > 0) { PHASE_D() }   // D(t-1): sspk3 stable until C(t) next interval

        // publish spikes as bits
        {
            unsigned long long bal0 = __ballot(spk0 > 0.5f);
            unsigned long long bal1 = __ballot(spk1 > 0.5f);
            unsigned long long bal2 = __ballot(spk2 > 0.5f);
            if (lane == 0) {
                sbh[wv][0] = bal0;
                sbh[wv][1] = bal1;
                sbh[wv][2] = bal2;
            }
        }

        // write x(t+1) (sx last read by A(t), which is behind the previous barrier)
        if (t + 1 < NT) {
            sxh[1 + t2]       = xp0;
            sxh[1 + t2 + 256] = xp1;
            if (t2 < LIN - 512) sxh[1 + t2 + 512] = xp2;
        }
        __syncthreads();   // sbits(t) ready; spool(t) consumed; sx(t+1) ready

        // ===== interval I1: A(t+1) | C(t) =====
        if (t + 1 < NT) {
            A_J(0) A_J(1) A_J(2) A_J(3) A_J(4)   // writes spool(t+1)
        }

        {
            unsigned long long M0 = sbh[s_ >> 3][0];
            unsigned long long M1 = sbh[s_ >> 3][1];
            unsigned long long M2 = sbh[s_ >> 3][2];
            uint32_t W0 = (uint32_t)(M0 >> cbsh);
            uint32_t W1 = (uint32_t)(M1 >> cbsh);
            uint32_t W2 = (uint32_t)(M2 >> cbsh);

            v2f a0v = {0.f, 0.f}, a1v = {0.f, 0.f}, a2v = {0.f, 0.f}, a3v = {0.f, 0.f};
            #pragma unroll
            for (int i = 0; i < 11; ++i) {
                const int o0 = 2 * i, o1 = 2 * i + 1;
                uint32_t wl0 = (o0 < 8) ? W0 : ((o0 < 16) ? W1 : W2);
                uint32_t wl1 = (o1 < 8) ? W0 : ((o1 < 16) ? W1 : W2);
                v2f fpi;
                fpi.x = (float)((wl0 >> ((o0 & 3) * 8 + ((o0 >> 2) & 1) * 4)) & 1u);
                fpi.y = (float)((wl1 >> ((o1 & 3) * 8 + ((o1 >> 2) & 1) * 4)) & 1u);
                float4 wa  = wrow[i * 64];          // {wj0p, wj1p}
                float4 wb4 = wrow[(11 + i) * 64];   // {wj2p, wj3p}
                a0v = pkfma((v2f){wa.x,  wa.y},  fpi, a0v);
                a1v = pkfma((v2f){wa.z,  wa.w},  fpi, a1v);
                a2v = pkfma((v2f){wb4.x, wb4.y}, fpi, a2v);
                a3v = pkfma((v2f){wb4.z, wb4.w}, fpi, a3v);
            }
            float a0 = red32(a0v.x + a0v.y);
            float a1 = red32(a1v.x + a1v.y);
            float a2 = red32(a2v.x + a2v.y);
            float a3 = red32(a3v.x + a3v.y);

            float r0 = (m30 > 1.f) ? 1.f : 0.f; m30 = 0.9f * m30 + (a0 + bC0) - r0;
            float r1 = (m31 > 1.f) ? 1.f : 0.f; m31 = 0.9f * m31 + (a1 + bC1) - r1;
            float r2 = (m32 > 1.f) ? 1.f : 0.f; m32 = 0.9f * m32 + (a2 + bC2) - r2;
            float r3 = (m33 > 1.f) ? 1.f : 0.f; m33 = 0.9f * m33 + (a3 + bC3) - r3;
            if (s_ == 0) {
                float4 st;
                st.x = (m30 > 1.f) ? 1.f : 0.f;
                st.y = (m31 > 1.f) ? 1.f : 0.f;
                st.z = (m32 > 1.f) ? 1.f : 0.f;
                st.w = (m33 > 1.f) ? 1.f : 0.f;
                *reinterpret_cast<float4*>(&sspk3h[jb]) = st;
            }
        }
        __syncthreads();   // sspk3(t) ready for D in next I2; spool(t+1) ready for B
    }

    // ---- epilogue: D(NT-1) ----
    PHASE_D()

    if (t2 == 0)  out[b * 2 + 0] = cnt;
    if (t2 == 32) out[b * 2 + 1] = cnt;
}

extern "C" void kernel_launch(void* const* d_in, const int* in_sizes, int n_in,
                              void* d_out, int out_size, void* d_ws, size_t ws_size,
                              hipStream_t stream) {
    const float* x   = (const float*)d_in[0];
    const float* w1  = (const float*)d_in[1];
    const float* b1  = (const float*)d_in[2];
    const float* w2  = (const float*)d_in[3];
    const float* b2  = (const float*)d_in[4];
    const float* wf1 = (const float*)d_in[5];
    const float* bf1 = (const float*)d_in[6];
    const float* wf2 = (const float*)d_in[7];
    const float* bf2 = (const float*)d_in[8];
    float* out = (float*)d_out;

    snn_all<<<NB / 2, 512, 0, stream>>>(x, w1, b1, w2, b2, wf1, bf1, wf2, bf2, out);
}

// Round 16
// 366.889 us; speedup vs baseline: 2.9328x; 1.0332x over previous
//
#include <hip/hip_runtime.h>
#include <stdint.h>

// SNN audio classifier. Round 16: 256 blocks x 512 threads; ALL 8 waves serve
// BOTH of the block's 2 samples (two interleaved copies of the verified
// round-13 512-thread phase bodies) -> intra-wave ILP fills the 43% VALU idle
// seen at 2 waves/SIMD. fc1 weight ds_reads amortize across samples.
// RS=82 bank fix + DPP red32 kept from round 15. Conv1 odd-window pairing
// dropped (-13 regs) to stay under the 128-VGPR budget (spill tripwire).

#define NB 512
#define NT 100
#define LIN 686
#define RS 82          // spool row stride in v2f

typedef float v2f __attribute__((ext_vector_type(2)));

__device__ __forceinline__ v2f pkfma(v2f a, v2f b, v2f c) {
    v2f d;
    asm("v_pk_fma_f32 %0, %1, %2, %3" : "=v"(d) : "v"(a), "v"(b), "v"(c));
    return d;
}

__device__ __forceinline__ float dpp_add8(float x) {   // sum over 8-lane groups
    int t;
    t = __builtin_amdgcn_mov_dpp(__float_as_int(x), 0x141, 0xf, 0xf, true); // row_half_mirror
    x += __int_as_float(t);
    t = __builtin_amdgcn_mov_dpp(__float_as_int(x), 0x1B, 0xf, 0xf, true);  // quad_perm [3,2,1,0]
    x += __int_as_float(t);
    t = __builtin_amdgcn_mov_dpp(__float_as_int(x), 0xB1, 0xf, 0xf, true);  // quad_perm [1,0,3,2]
    x += __int_as_float(t);
    return x;
}

__device__ __forceinline__ float red32(float x) {      // sum over 32-lane groups
    int t;
    t = __builtin_amdgcn_mov_dpp(__float_as_int(x), 0xB1, 0xf, 0xf, true);  // xor1
    x += __int_as_float(t);
    t = __builtin_amdgcn_mov_dpp(__float_as_int(x), 0x4E, 0xf, 0xf, true);  // xor2
    x += __int_as_float(t);
    t = __builtin_amdgcn_mov_dpp(__float_as_int(x), 0x124, 0xf, 0xf, true); // row_ror:4
    x += __int_as_float(t);
    t = __builtin_amdgcn_mov_dpp(__float_as_int(x), 0x128, 0xf, 0xf, true); // row_ror:8
    x += __int_as_float(t);
    t = __builtin_amdgcn_ds_swizzle(__float_as_int(x), 0x401F);             // xor16
    x += __int_as_float(t);
    return x;
}

// bit(o) of the published spk2 ballots (512-thr layout, round-13-verified):
//   o<16 -> W1[(o>>2)&1], shift 4*((o>>3)&1)+8*(o&3);  o>=16 -> W2[(o>>2)&1], shift 8*(o&3)
#define FBIT(W1L, W1H, W2L, W2H, o) \
    ((float)(((((o) < 16) ? ((((o) >> 2) & 1) ? (W1H) : (W1L)) \
                          : ((((o) >> 2) & 1) ? (W2H) : (W2L))) >> \
              (((o) < 16) ? (4 * (((o) >> 3) & 1) + 8 * ((o) & 3)) : (8 * ((o) & 3)))) & 1u))

__global__
__attribute__((amdgpu_flat_work_group_size(512, 512)))
__attribute__((amdgpu_waves_per_eu(1, 2)))
void snn_all(
    const float* __restrict__ x,
    const float* __restrict__ w1, const float* __restrict__ b1,
    const float* __restrict__ w2, const float* __restrict__ b2,
    const float* __restrict__ wf1, const float* __restrict__ bf1,
    const float* __restrict__ wf2, const float* __restrict__ bf2,
    float* __restrict__ out)
{
    // fc1 weights: f4[g*352 + i*32 + s] = {w[2g][s*22+2i], w[2g][s*22+2i+1],
    //                                      w[2g+1][s*22+2i], w[2g+1][s*22+2i+1]}
    __shared__ __align__(16) float swf1r[5632 * 4];            // 90112 B, shared
    __shared__ __align__(16) float sx[2][LIN + 2];
    __shared__ __align__(16) float spool2f[2][8 * RS * 2];
    __shared__ unsigned long long sbits[2][8][2];
    __shared__ __align__(8) float sspk3[2][32];

    const int t2   = threadIdx.x;      // 0..511
    const int b0   = blockIdx.x * 2;   // this block's two samples: b0, b0+1
    const int lane = t2 & 63;
    const int wv   = t2 >> 6;          // wave 0..7

    // ---------------- one-time init: reorder wf1 into LDS ----------------
    for (int d = t2; d < 5632; d += 512) {
        int g = d / 352;
        int r = d - g * 352;
        int i = r >> 5;
        int s = r & 31;
        float4 v;
        v.x = wf1[(2 * g)     * 704 + s * 22 + 2 * i];
        v.y = wf1[(2 * g)     * 704 + s * 22 + 2 * i + 1];
        v.z = wf1[(2 * g + 1) * 704 + s * 22 + 2 * i];
        v.w = wf1[(2 * g + 1) * 704 + s * 22 + 2 * i + 1];
        reinterpret_cast<float4*>(swf1r)[d] = v;
    }

    // ---- phase A setup: conv1. thread = (ca = t2&15, pg = t2>>4 in 0..31) ----
    const int ca = t2 & 15;
    const int pg = t2 >> 4;
    float wAs[13];
    #pragma unroll
    for (int k = 0; k < 13; ++k) wAs[k] = w1[ca * 13 + k];
    v2f we0 = {wAs[0], wAs[1]}, we1 = {wAs[2], wAs[3]}, we2 = {wAs[4], wAs[5]},
        we3 = {wAs[6], wAs[7]}, we4 = {wAs[8], wAs[9]}, we5 = {wAs[10], wAs[11]};
    const float wA12s = wAs[12];
    const float bA = b1[ca];
    float m1a0[3], m1b0[3], m1a1[3], m1b1[3];
    #pragma unroll
    for (int j = 0; j < 3; ++j) { m1a0[j] = 0.f; m1b0[j] = 0.f; m1a1[j] = 0.f; m1b1[j] = 0.f; }

    // ---- phase B setup: conv2. wave wv owns channel quartet 4wv..4wv+3 ----
    const int ip  = lane & 7;          // row-pair (conv1 rows 2ip, 2ip+1)
    const int og  = (lane >> 3) & 3;   // output phase
    const int omh = lane >> 5;         // window triple: om = {omh, 2+omh, 4+omh}
    const int ccq = ip & 3;            // owned channel within quartet
    v2f wp0[7], wp1[7], wp2[7], wp3[7];
    #pragma unroll
    for (int k = 0; k < 7; ++k) {
        int base0 = (wv * 4 + 0) * 112 + 14 * ip + k;
        int base1 = (wv * 4 + 1) * 112 + 14 * ip + k;
        int base2 = (wv * 4 + 2) * 112 + 14 * ip + k;
        int base3 = (wv * 4 + 3) * 112 + 14 * ip + k;
        wp0[k].x = w2[base0]; wp0[k].y = w2[base0 + 7];
        wp1[k].x = w2[base1]; wp1[k].y = w2[base1 + 7];
        wp2[k].x = w2[base2]; wp2[k].y = w2[base2 + 7];
        wp3[k].x = w2[base3]; wp3[k].y = w2[base3 + 7];
    }
    const float bB = b2[wv * 4 + ccq];
    float mA0 = 0.f, mB0 = 0.f, mA1 = 0.f, mB1 = 0.f;

    // ---- phase C setup: group gC = wv*2 + sub handles outputs 2gC, 2gC+1 ----
    const int sub = (t2 >> 5) & 1;
    const int gC  = wv * 2 + sub;
    const int s_  = t2 & 31;
    const float bC0 = bf1[2 * gC], bC1 = bf1[2 * gC + 1];
    float m30_0 = 0.f, m31_0 = 0.f, m30_1 = 0.f, m31_1 = 0.f;
    const int q_  = s_ >> 2;           // wave (quartet) holding channel s_
    const int cc_ = s_ & 3;            // channel within quartet

    // ---- phase D setup: fc2 ----
    float wD = 0.f, bD = 0.f;
    if (t2 < 64) {
        wD = wf2[(t2 >> 5) * 32 + (t2 & 31)];
        if ((t2 & 31) == 0) bD = bf2[t2 >> 5];
    }
    float m4_0 = 0.f, cnt_0 = 0.f, m4_1 = 0.f, cnt_1 = 0.f;

    // ---- init LDS ----
    for (int i = t2; i < 2 * 8 * RS * 2; i += 512) ((float*)spool2f)[i] = 0.f;
    const float* xb0p = x + (size_t)b0 * NT * LIN;
    const float* xb1p = xb0p + (size_t)NT * LIN;
    if (t2 == 0) { sx[0][0] = 0.f; sx[0][LIN + 1] = 0.f; sx[1][0] = 0.f; sx[1][LIN + 1] = 0.f; }
    sx[0][1 + t2] = xb0p[t2];
    sx[1][1 + t2] = xb1p[t2];
    if (t2 < LIN - 512) {
        sx[0][1 + t2 + 512] = xb0p[t2 + 512];
        sx[1][1 + t2 + 512] = xb1p[t2 + 512];
    }
    __syncthreads();

    const v2f* sp0v = reinterpret_cast<const v2f*>(spool2f[0]);
    const v2f* sp1v = reinterpret_cast<const v2f*>(spool2f[1]);
    const v2f* wbA  = sp0v + ip * RS + 3 * og + 12 * omh;    // sample0 window base
    const v2f* wbB  = sp1v + ip * RS + 3 * og + 12 * omh;    // sample1 window base
    const float4* wrow = reinterpret_cast<const float4*>(swf1r) + gC * 352 + s_;

// ===== phase A (3-slot, 512-thr): conv1 + LIF1 + maxpool2 =====
// a0 via v2f pairings; a1 via scalar fma on pairing components (saves wo regs)
#define A_J3(j, SXH, SPOOLH, M1A, M1B) { \
    const int p_ = ((j) == 2) ? (64 + pg) : (pg + 32 * (j)); \
    if ((j) < 2 || pg < 4) { \
        const v2f* qv_ = reinterpret_cast<const v2f*>((SXH) + 10 * p_); \
        v2f q0_ = qv_[0], q1_ = qv_[1], q2_ = qv_[2], q3_ = qv_[3], q4_ = qv_[4], \
            q5_ = qv_[5], q6_ = qv_[6], q7_ = qv_[7], q8_ = qv_[8]; \
        v2f va_ = {0.f, 0.f}; \
        va_ = pkfma(we0, q0_, va_); va_ = pkfma(we1, q1_, va_); \
        va_ = pkfma(we2, q2_, va_); va_ = pkfma(we3, q3_, va_); \
        va_ = pkfma(we4, q4_, va_); va_ = pkfma(we5, q5_, va_); \
        float a0_ = (va_.x + va_.y) + wA12s * q6_.x; \
        float a1_ = we0.x * q2_.y; \
        a1_ = fmaf(we0.y, q3_.x, a1_); a1_ = fmaf(we1.x, q3_.y, a1_); \
        a1_ = fmaf(we1.y, q4_.x, a1_); a1_ = fmaf(we2.x, q4_.y, a1_); \
        a1_ = fmaf(we2.y, q5_.x, a1_); a1_ = fmaf(we3.x, q5_.y, a1_); \
        a1_ = fmaf(we3.y, q6_.x, a1_); a1_ = fmaf(we4.x, q6_.y, a1_); \
        a1_ = fmaf(we4.y, q7_.x, a1_); a1_ = fmaf(we5.x, q7_.y, a1_); \
        a1_ = fmaf(we5.y, q8_.x, a1_); a1_ = fmaf(wA12s, q8_.y, a1_); \
        float m0_ = (M1A)[(j)], mm_ = (M1B)[(j)]; \
        float r0_ = (m0_ > 1.f) ? 1.f : 0.f; \
        float r1_ = (mm_ > 1.f) ? 1.f : 0.f; \
        m0_ = 0.9f * m0_ + (a0_ + bA) - r0_; \
        mm_ = 0.9f * mm_ + (a1_ + bA) - r1_; \
        (M1A)[(j)] = m0_; (M1B)[(j)] = mm_; \
        (SPOOLH)[((ca >> 1) * RS + 1 + p_) * 2 + (ca & 1)] = \
            (m0_ > 1.f || mm_ > 1.f) ? 1.f : 0.f; \
    } }

// ===== phase B window: 7 v2f taps, 4 channels, dpp reduce; owner per COND =====
#define B_WIN(WB, COND, MSLOT, SPK) { \
    v2f t0_ = (WB)[0], t1_ = (WB)[1], t2v_ = (WB)[2], t3_ = (WB)[3], \
        t4_ = (WB)[4], t5_ = (WB)[5], t6_ = (WB)[6]; \
    v2f a0_ = {0.f, 0.f}, a1_ = {0.f, 0.f}, a2_ = {0.f, 0.f}, a3_ = {0.f, 0.f}; \
    a0_ = pkfma(wp0[0], t0_, a0_); a1_ = pkfma(wp1[0], t0_, a1_); \
    a2_ = pkfma(wp2[0], t0_, a2_); a3_ = pkfma(wp3[0], t0_, a3_); \
    a0_ = pkfma(wp0[1], t1_, a0_); a1_ = pkfma(wp1[1], t1_, a1_); \
    a2_ = pkfma(wp2[1], t1_, a2_); a3_ = pkfma(wp3[1], t1_, a3_); \
    a0_ = pkfma(wp0[2], t2v_, a0_); a1_ = pkfma(wp1[2], t2v_, a1_); \
    a2_ = pkfma(wp2[2], t2v_, a2_); a3_ = pkfma(wp3[2], t2v_, a3_); \
    a0_ = pkfma(wp0[3], t3_, a0_); a1_ = pkfma(wp1[3], t3_, a1_); \
    a2_ = pkfma(wp2[3], t3_, a2_); a3_ = pkfma(wp3[3], t3_, a3_); \
    a0_ = pkfma(wp0[4], t4_, a0_); a1_ = pkfma(wp1[4], t4_, a1_); \
    a2_ = pkfma(wp2[4], t4_, a2_); a3_ = pkfma(wp3[4], t4_, a3_); \
    a0_ = pkfma(wp0[5], t5_, a0_); a1_ = pkfma(wp1[5], t5_, a1_); \
    a2_ = pkfma(wp2[5], t5_, a2_); a3_ = pkfma(wp3[5], t5_, a3_); \
    a0_ = pkfma(wp0[6], t6_, a0_); a1_ = pkfma(wp1[6], t6_, a1_); \
    a2_ = pkfma(wp2[6], t6_, a2_); a3_ = pkfma(wp3[6], t6_, a3_); \
    float s0_ = dpp_add8(a0_.x + a0_.y); \
    float s1_ = dpp_add8(a1_.x + a1_.y); \
    float s2_ = dpp_add8(a2_.x + a2_.y); \
    float s3_ = dpp_add8(a3_.x + a3_.y); \
    float sc_ = (ccq == 0) ? s0_ : ((ccq == 1) ? s1_ : ((ccq == 2) ? s2_ : s3_)); \
    if (COND) { \
        float mm_ = MSLOT; \
        float rr_ = (mm_ > 1.f) ? 1.f : 0.f; \
        mm_ = 0.9f * mm_ + (sc_ + bB) - rr_; \
        MSLOT = mm_; \
        SPK = (mm_ > 1.f) ? 1.f : 0.f; \
    } }

// ===== phase D: fc2 (32->2) + LIF4 + count =====
#define PHASE_D(SP3, M4, CNT) { \
    if (t2 < 64) { \
        float v = (SP3)[t2 & 31] * wD; \
        v += __shfl_xor(v, 16, 32); \
        v += __shfl_xor(v, 8, 32); \
        v += __shfl_xor(v, 4, 32); \
        v += __shfl_xor(v, 2, 32); \
        v += __shfl_xor(v, 1, 32); \
        if ((t2 & 31) == 0) { \
            float rr = (M4 > 1.f) ? 1.f : 0.f; \
            M4 = 0.9f * M4 + (v + bD) - rr; \
            if (M4 > 1.f) CNT += 1.f; \
        } \
    } }

    // ---- prologue: A(0) both samples ----
    A_J3(0, sx[0], spool2f[0], m1a0, m1b0)
    A_J3(1, sx[0], spool2f[0], m1a0, m1b0)
    A_J3(2, sx[0], spool2f[0], m1a0, m1b0)
    A_J3(0, sx[1], spool2f[1], m1a1, m1b1)
    A_J3(1, sx[1], spool2f[1], m1a1, m1b1)
    A_J3(2, sx[1], spool2f[1], m1a1, m1b1)
    __syncthreads();   // spool(0) ready

    for (int t = 0; t < NT; ++t) {
        // ===== interval I2: B(t) s0+s1 | D(t-1) s0+s1 | x(t+1) prefetch =====
        float xpA0 = 0.f, xpA1 = 0.f, xpB0 = 0.f, xpB1 = 0.f;
        if (t + 1 < NT) {
            const float* xt0 = xb0p + (size_t)(t + 1) * LIN;
            const float* xt1 = xb1p + (size_t)(t + 1) * LIN;
            xpA0 = xt0[t2];
            xpB0 = xt1[t2];
            if (t2 < LIN - 512) { xpA1 = xt0[t2 + 512]; xpB1 = xt1[t2 + 512]; }
        }

        float spkA0 = 0.f, spkB0 = 0.f, spkA1 = 0.f, spkB1 = 0.f;
        B_WIN(wbA,      ip < 4,  mA0, spkA0)
        B_WIN(wbA + 24, ip >= 4, mA0, spkA0)
        if (omh == 0 || og < 2) { B_WIN(wbA + 48, ip < 4, mB0, spkB0) }
        B_WIN(wbB,      ip < 4,  mA1, spkA1)
        B_WIN(wbB + 24, ip >= 4, mA1, spkA1)
        if (omh == 0 || og < 2) { B_WIN(wbB + 48, ip < 4, mB1, spkB1) }

        if (t > 0) {
            PHASE_D(sspk3[0], m4_0, cnt_0)
            PHASE_D(sspk3[1], m4_1, cnt_1)
        }

        // publish spikes
        {
            unsigned long long balA1 = __ballot(spkA0 > 0.5f);
            unsigned long long balA2 = __ballot(spkB0 > 0.5f);
            unsigned long long balB1 = __ballot(spkA1 > 0.5f);
            unsigned long long balB2 = __ballot(spkB1 > 0.5f);
            if (lane == 0) {
                sbits[0][wv][0] = balA1; sbits[0][wv][1] = balA2;
                sbits[1][wv][0] = balB1; sbits[1][wv][1] = balB2;
            }
        }

        // write x(t+1) (sx last read by A(t), behind the previous barrier)
        if (t + 1 < NT) {
            sx[0][1 + t2] = xpA0;
            sx[1][1 + t2] = xpB0;
            if (t2 < LIN - 512) { sx[0][1 + t2 + 512] = xpA1; sx[1][1 + t2 + 512] = xpB1; }
        }
        __syncthreads();   // sbits(t) ready; spool(t) consumed; sx(t+1) ready

        // ===== interval I1: A(t+1) s0+s1 | C(t) s0+s1 (fused weight loads) =====
        if (t + 1 < NT) {
            A_J3(0, sx[0], spool2f[0], m1a0, m1b0)
            A_J3(1, sx[0], spool2f[0], m1a0, m1b0)
            A_J3(2, sx[0], spool2f[0], m1a0, m1b0)
            A_J3(0, sx[1], spool2f[1], m1a1, m1b1)
            A_J3(1, sx[1], spool2f[1], m1a1, m1b1)
            A_J3(2, sx[1], spool2f[1], m1a1, m1b1)
        }

        {
            unsigned long long M10 = sbits[0][q_][0] >> cc_;
            unsigned long long M20 = sbits[0][q_][1] >> cc_;
            unsigned long long M11 = sbits[1][q_][0] >> cc_;
            unsigned long long M21 = sbits[1][q_][1] >> cc_;
            uint32_t A1lo = (uint32_t)M10, A1hi = (uint32_t)(M10 >> 32);
            uint32_t A2lo = (uint32_t)M20, A2hi = (uint32_t)(M20 >> 32);
            uint32_t B1lo = (uint32_t)M11, B1hi = (uint32_t)(M11 >> 32);
            uint32_t B2lo = (uint32_t)M21, B2hi = (uint32_t)(M21 >> 32);

            v2f a0v0 = {0.f, 0.f}, a1v0 = {0.f, 0.f}, a0v1 = {0.f, 0.f}, a1v1 = {0.f, 0.f};
            #pragma unroll
            for (int i = 0; i < 11; ++i) {
                v2f f0, f1;
                f0.x = FBIT(A1lo, A1hi, A2lo, A2hi, 2 * i);
                f0.y = FBIT(A1lo, A1hi, A2lo, A2hi, 2 * i + 1);
                f1.x = FBIT(B1lo, B1hi, B2lo, B2hi, 2 * i);
                f1.y = FBIT(B1lo, B1hi, B2lo, B2hi, 2 * i + 1);
                float4 wa = wrow[i * 32];            // one load serves both samples
                a0v0 = pkfma((v2f){wa.x, wa.y}, f0, a0v0);
                a1v0 = pkfma((v2f){wa.z, wa.w}, f0, a1v0);
                a0v1 = pkfma((v2f){wa.x, wa.y}, f1, a0v1);
                a1v1 = pkfma((v2f){wa.z, wa.w}, f1, a1v1);
            }
            float a00 = red32(a0v0.x + a0v0.y);
            float a10 = red32(a1v0.x + a1v0.y);
            float a01 = red32(a0v1.x + a0v1.y);
            float a11 = red32(a1v1.x + a1v1.y);

            float r0 = (m30_0 > 1.f) ? 1.f : 0.f; m30_0 = 0.9f * m30_0 + (a00 + bC0) - r0;
            float r1 = (m31_0 > 1.f) ? 1.f : 0.f; m31_0 = 0.9f * m31_0 + (a10 + bC1) - r1;
            float r2 = (m30_1 > 1.f) ? 1.f : 0.f; m30_1 = 0.9f * m30_1 + (a01 + bC0) - r2;
            float r3 = (m31_1 > 1.f) ? 1.f : 0.f; m31_1 = 0.9f * m31_1 + (a11 + bC1) - r3;
            if (s_ == 0) {
                float2 st0, st1;
                st0.x = (m30_0 > 1.f) ? 1.f : 0.f;
                st0.y = (m31_0 > 1.f) ? 1.f : 0.f;
                st1.x = (m30_1 > 1.f) ? 1.f : 0.f;
                st1.y = (m31_1 > 1.f) ? 1.f : 0.f;
                *reinterpret_cast<float2*>(&sspk3[0][2 * gC]) = st0;
                *reinterpret_cast<float2*>(&sspk3[1][2 * gC]) = st1;
            }
        }
        __syncthreads();   // sspk3(t) ready for D in next I2; spool(t+1) ready
    }

    // ---- epilogue: D(NT-1) both samples ----
    PHASE_D(sspk3[0], m4_0, cnt_0)
    PHASE_D(sspk3[1], m4_1, cnt_1)

    if (t2 == 0)  { out[b0 * 2 + 0] = cnt_0; out[(b0 + 1) * 2 + 0] = cnt_1; }
    if (t2 == 32) { out[b0 * 2 + 1] = cnt_0; out[(b0 + 1) * 2 + 1] = cnt_1; }
}

extern "C" void kernel_launch(void* const* d_in, const int* in_sizes, int n_in,
                              void* d_out, int out_size, void* d_ws, size_t ws_size,
                              hipStream_t stream) {
    const float* x   = (const float*)d_in[0];
    const float* w1  = (const float*)d_in[1];
    const float* b1  = (const float*)d_in[2];
    const float* w2  = (const float*)d_in[3];
    const float* b2  = (const float*)d_in[4];
    const float* wf1 = (const float*)d_in[5];
    const float* bf1 = (const float*)d_in[6];
    const float* wf2 = (const float*)d_in[7];
    const float* bf2 = (const float*)d_in[8];
    float* out = (float*)d_out;

    snn_all<<<NB / 2, 512, 0, stream>>>(x, w1, b1, w2, b2, wf1, bf1, wf2, bf2, out);
}